// Round 5
// baseline (957.009 us; speedup 1.0000x reference)
//
#include <hip/hip_runtime.h>
#include <hip/hip_bf16.h>

#define NN 20000
#define DD 512
#define EE 150000

typedef __attribute__((ext_vector_type(8))) short short8;
typedef __attribute__((ext_vector_type(4))) float floatx4;

static __device__ __forceinline__ float bfbits2f(unsigned short u) {
    unsigned int x = ((unsigned int)u) << 16;
    return __uint_as_float(x);
}

// ---------------- convert fp32 -> bf16 ----------------
__global__ __launch_bounds__(256) void k_convert_bf16(const float* __restrict__ in,
                                                      __hip_bfloat16* __restrict__ out, int n4) {
    int i = blockIdx.x * blockDim.x + threadIdx.x;
    if (i >= n4) return;
    float4 v = ((const float4*)in)[i];
    union { __hip_bfloat16 b[4]; ushort4 u; } cv;
    cv.b[0] = __float2bfloat16(v.x);
    cv.b[1] = __float2bfloat16(v.y);
    cv.b[2] = __float2bfloat16(v.z);
    cv.b[3] = __float2bfloat16(v.w);
    *(ushort4*)(out + 4l * i) = cv.u;
}

// ---------------- 512x512 transpose + convert to bf16 ----------------
__global__ __launch_bounds__(1024) void k_transpose_bf16(const float* __restrict__ in,
                                                         __hip_bfloat16* __restrict__ out) {
    __shared__ float tile[32][33];
    int bx = blockIdx.x * 32;
    int by = blockIdx.y * 32;
    int tx = threadIdx.x, ty = threadIdx.y;
    tile[ty][tx] = in[(by + ty) * 512 + bx + tx];
    __syncthreads();
    out[(bx + ty) * 512 + by + tx] = __float2bfloat16(tile[tx][ty]);
}

// ---------------- bf16 MFMA GEMM: C[M,512] = A[M,512] @ B ----------------
// Barrier-free, LDS-free: rounds 1-4 showed every LDS-staged variant pinned
// at 51-61us regardless of traffic/occupancy -> the per-K-phase vmcnt(0)+
// s_barrier drain is structural. Here each wave owns a 64x64 tile and loads
// its MFMA fragments DIRECTLY global->VGPR (each fragment = 16 contiguous
// B/lane, 16 cachelines/instr = same line count as ideal coalescing),
// software-pipelined one K-step ahead. 4 waves/block share rows (A L1 reuse);
// B (0.5 MB) stays L2-resident. No __syncthreads in the whole kernel.
// mode 0: Cb = bf16(C). mode 1: Cf = relu(C + bf16 addend).
__global__ __launch_bounds__(256)
void k_gemm(const __hip_bfloat16* __restrict__ A, const __hip_bfloat16* __restrict__ Bt,
            float* __restrict__ Cf, __hip_bfloat16* __restrict__ Cb,
            const __hip_bfloat16* __restrict__ addend, int M, int mode) {
    const int tid = threadIdx.x;
    const int lane = tid & 63;
    const int wave = tid >> 6;
    const int row0 = blockIdx.x * 64;
    const int col0 = blockIdx.y * 256 + wave * 64;  // wave owns 64 cols
    const int q8 = lane >> 4;
    const int l15 = lane & 15;

    const __hip_bfloat16* ap[4];
    const __hip_bfloat16* bp[4];
#pragma unroll
    for (int mi = 0; mi < 4; mi++) {
        int r = row0 + mi * 16 + l15;
        if (r >= M) r = M - 1;
        ap[mi] = A + (size_t)r * DD + q8 * 8;
    }
#pragma unroll
    for (int ni = 0; ni < 4; ni++)
        bp[ni] = Bt + (size_t)(col0 + ni * 16 + l15) * DD + q8 * 8;

    floatx4 acc[4][4];
#pragma unroll
    for (int a = 0; a < 4; a++)
#pragma unroll
        for (int b = 0; b < 4; b++) acc[a][b] = (floatx4){0.f, 0.f, 0.f, 0.f};

    short8 aF[4], bF[4];
#pragma unroll
    for (int i = 0; i < 4; i++) {
        aF[i] = *(const short8*)ap[i];
        bF[i] = *(const short8*)bp[i];
    }
    for (int kb = 0; kb < 15; kb++) {
        short8 aN[4], bN[4];
        const int ko = (kb + 1) * 32;
#pragma unroll
        for (int i = 0; i < 4; i++) {
            aN[i] = *(const short8*)(ap[i] + ko);
            bN[i] = *(const short8*)(bp[i] + ko);
        }
#pragma unroll
        for (int mi = 0; mi < 4; mi++)
#pragma unroll
            for (int ni = 0; ni < 4; ni++)
                acc[mi][ni] =
                    __builtin_amdgcn_mfma_f32_16x16x32_bf16(aF[mi], bF[ni], acc[mi][ni], 0, 0, 0);
#pragma unroll
        for (int i = 0; i < 4; i++) {
            aF[i] = aN[i];
            bF[i] = bN[i];
        }
    }
#pragma unroll
    for (int mi = 0; mi < 4; mi++)
#pragma unroll
        for (int ni = 0; ni < 4; ni++)
            acc[mi][ni] =
                __builtin_amdgcn_mfma_f32_16x16x32_bf16(aF[mi], bF[ni], acc[mi][ni], 0, 0, 0);

#pragma unroll
    for (int mi = 0; mi < 4; mi++)
#pragma unroll
        for (int ni = 0; ni < 4; ni++)
#pragma unroll
            for (int r = 0; r < 4; r++) {
                int grow = row0 + mi * 16 + q8 * 4 + r;
                int gcol = col0 + ni * 16 + l15;
                if (grow < M) {
                    float v = acc[mi][ni][r];
                    size_t idx = (size_t)grow * DD + gcol;
                    if (mode == 0) Cb[idx] = __float2bfloat16(v);
                    else {
                        v += bfbits2f(*(const unsigned short*)(addend + idx));
                        Cf[idx] = v > 0.f ? v : 0.f;
                    }
                }
            }
}

// ---------------- el/er: per-row dot products ----------------
__global__ __launch_bounds__(256)
void k_el_er(const __hip_bfloat16* __restrict__ h, const float* __restrict__ al,
             const float* __restrict__ ar, float* __restrict__ el, float* __restrict__ er) {
    int wave = threadIdx.x >> 6, lane = threadIdx.x & 63;
    int row = blockIdx.x * 4 + wave;
    if (row >= NN) return;
    uint4 hv = *(const uint4*)(h + (size_t)row * 512 + lane * 8);
    const unsigned short* hs = (const unsigned short*)&hv;
    float4 a0 = *(const float4*)(al + lane * 8);
    float4 a1 = *(const float4*)(al + lane * 8 + 4);
    float4 r0 = *(const float4*)(ar + lane * 8);
    float4 r1 = *(const float4*)(ar + lane * 8 + 4);
    float hf[8];
#pragma unroll
    for (int j = 0; j < 8; j++) hf[j] = bfbits2f(hs[j]);
    float sl = hf[0] * a0.x + hf[1] * a0.y + hf[2] * a0.z + hf[3] * a0.w +
               hf[4] * a1.x + hf[5] * a1.y + hf[6] * a1.z + hf[7] * a1.w;
    float sr = hf[0] * r0.x + hf[1] * r0.y + hf[2] * r0.z + hf[3] * r0.w +
               hf[4] * r1.x + hf[5] * r1.y + hf[6] * r1.z + hf[7] * r1.w;
#pragma unroll
    for (int off = 32; off > 0; off >>= 1) {
        sl += __shfl_down(sl, off);
        sr += __shfl_down(sr, off);
    }
    if (lane == 0) {
        el[row] = sl;
        er[row] = sr;
    }
}

// ---------------- CSR build (batched over 4 relations, hoisted pre-loop) ----------------
__global__ void k_zero_i32(int* p, int n) {
    int i = blockIdx.x * blockDim.x + threadIdx.x;
    if (i < n) p[i] = 0;
}

__global__ void k_count4(const int* __restrict__ e0, const int* __restrict__ e1,
                         const int* __restrict__ e2, const int* __restrict__ e3,
                         int* __restrict__ deg4) {
    int g = blockIdx.x * blockDim.x + threadIdx.x;
    if (g >= 4 * EE) return;
    int rel = g / EE;
    int e = g - rel * EE;
    const int* ed = rel == 0 ? e0 : rel == 1 ? e1 : rel == 2 ? e2 : e3;
    atomicAdd(&deg4[rel * NN + ed[EE + e]], 1);
}

__global__ __launch_bounds__(1024)
void k_scan4(const int* __restrict__ deg4, int* __restrict__ rp4, int* __restrict__ cur4) {
    const int rel = blockIdx.x;
    const int* deg = deg4 + rel * NN;
    int* row_ptr = rp4 + rel * (NN + 1);
    int* cursor = cur4 + rel * NN;
    __shared__ int sm[1024];
    int t = threadIdx.x;
    const int CH = 20;
    int begin = t * CH;
    int end = begin + CH;
    if (end > NN) end = NN;
    int s = 0;
    if (begin < NN)
        for (int i = begin; i < end; i++) s += deg[i];
    sm[t] = s;
    __syncthreads();
    for (int off = 1; off < 1024; off <<= 1) {
        int v = (t >= off) ? sm[t - off] : 0;
        __syncthreads();
        sm[t] += v;
        __syncthreads();
    }
    int run = sm[t] - s;
    if (begin < NN) {
        for (int i = begin; i < end; i++) {
            row_ptr[i] = run;
            cursor[i] = run;
            run += deg[i];
        }
        if (end == NN) row_ptr[NN] = run;
    }
}

__global__ void k_scatter4(const int* __restrict__ e0, const int* __restrict__ e1,
                           const int* __restrict__ e2, const int* __restrict__ e3,
                           int* __restrict__ cur4, int* __restrict__ csr4) {
    int g = blockIdx.x * blockDim.x + threadIdx.x;
    if (g >= 4 * EE) return;
    int rel = g / EE;
    int e = g - rel * EE;
    const int* ed = rel == 0 ? e0 : rel == 1 ? e1 : rel == 2 ? e2 : e3;
    int dst = ed[EE + e];
    int pos = atomicAdd(&cur4[rel * NN + dst], 1);
    csr4[rel * EE + pos] = ed[e];
}

// ---------------- fused edge-softmax + aggregate, wave per dst ----------------
__global__ __launch_bounds__(256)
void k_agg_fused(const int* __restrict__ row_ptr, const int* __restrict__ csr_src,
                 const float* __restrict__ el, const float* __restrict__ er,
                 const __hip_bfloat16* __restrict__ h, const float* __restrict__ out_prev,
                 const float* __restrict__ bias, __hip_bfloat16* __restrict__ t_out,
                 float* __restrict__ alpha_tmp, int use_prev) {
    int d = (blockIdx.x * blockDim.x + threadIdx.x) >> 6;
    int lane = threadIdx.x & 63;
    if (d >= NN) return;
    int s0 = row_ptr[d], s1 = row_ptr[d + 1];
    int deg = s1 - s0;
    int base = lane * 8;
    float acc[8] = {0.f, 0.f, 0.f, 0.f, 0.f, 0.f, 0.f, 0.f};

    if (deg <= 64) {
        int sv = 0;
        float av = 0.f;
        if (lane < deg) sv = csr_src[s0 + lane];
        float erd = er[d];
        float v = -1e30f;
        if (lane < deg) {
            float e = el[sv] + erd;
            v = e >= 0.f ? e : 0.2f * e;
        }
        float m = v;
#pragma unroll
        for (int off = 32; off > 0; off >>= 1) m = fmaxf(m, __shfl_xor(m, off));
        float wgt = (lane < deg) ? __expf(v - m) : 0.f;
        float s = wgt;
#pragma unroll
        for (int off = 32; off > 0; off >>= 1) s += __shfl_xor(s, off);
        av = wgt / s;
        int t = 0;
        for (; t + 1 < deg; t += 2) {
            int sA = __shfl(sv, t), sB = __shfl(sv, t + 1);
            float aA = __shfl(av, t), aB = __shfl(av, t + 1);
            uint4 hv0 = *(const uint4*)(h + (size_t)sA * DD + base);
            uint4 hv1 = *(const uint4*)(h + (size_t)sB * DD + base);
            const unsigned short* h0 = (const unsigned short*)&hv0;
            const unsigned short* h1 = (const unsigned short*)&hv1;
#pragma unroll
            for (int k = 0; k < 8; k++) acc[k] += aA * bfbits2f(h0[k]) + aB * bfbits2f(h1[k]);
        }
        if (t < deg) {
            int sA = __shfl(sv, t);
            float aA = __shfl(av, t);
            uint4 hv0 = *(const uint4*)(h + (size_t)sA * DD + base);
            const unsigned short* h0 = (const unsigned short*)&hv0;
#pragma unroll
            for (int k = 0; k < 8; k++) acc[k] += aA * bfbits2f(h0[k]);
        }
    } else {
        float erd = er[d];
        float m = -1e30f;
        for (int j = s0 + lane; j < s1; j += 64) {
            float e = el[csr_src[j]] + erd;
            e = e >= 0.f ? e : 0.2f * e;
            alpha_tmp[j] = e;
            m = fmaxf(m, e);
        }
#pragma unroll
        for (int off = 32; off > 0; off >>= 1) m = fmaxf(m, __shfl_xor(m, off));
        float s = 0.f;
        for (int j = s0 + lane; j < s1; j += 64) {
            float wv = __expf(alpha_tmp[j] - m);
            alpha_tmp[j] = wv;
            s += wv;
        }
#pragma unroll
        for (int off = 32; off > 0; off >>= 1) s += __shfl_xor(s, off);
        float inv = 1.f / s;
        for (int j0 = 0; j0 < deg; j0 += 64) {
            int cnt = deg - j0;
            if (cnt > 64) cnt = 64;
            int sv = 0;
            float av = 0.f;
            if (lane < cnt) {
                sv = csr_src[s0 + j0 + lane];
                av = alpha_tmp[s0 + j0 + lane] * inv;
            }
            for (int t = 0; t < cnt; t++) {
                int sA = __shfl(sv, t);
                float aA = __shfl(av, t);
                uint4 hv0 = *(const uint4*)(h + (size_t)sA * DD + base);
                const unsigned short* h0 = (const unsigned short*)&hv0;
#pragma unroll
                for (int k = 0; k < 8; k++) acc[k] += aA * bfbits2f(h0[k]);
            }
        }
    }

    if (use_prev) {
        float4 p0 = *(const float4*)(out_prev + (size_t)d * DD + base);
        float4 p1 = *(const float4*)(out_prev + (size_t)d * DD + base + 4);
        acc[0] += p0.x; acc[1] += p0.y; acc[2] += p0.z; acc[3] += p0.w;
        acc[4] += p1.x; acc[5] += p1.y; acc[6] += p1.z; acc[7] += p1.w;
    }
    float4 b0 = *(const float4*)(bias + base);
    float4 b1 = *(const float4*)(bias + base + 4);
    acc[0] += b0.x; acc[1] += b0.y; acc[2] += b0.z; acc[3] += b0.w;
    acc[4] += b1.x; acc[5] += b1.y; acc[6] += b1.z; acc[7] += b1.w;
    union { __hip_bfloat16 b[8]; uint4 u; } cv;
#pragma unroll
    for (int k = 0; k < 8; k++) cv.b[k] = __float2bfloat16(acc[k]);
    *(uint4*)(t_out + (size_t)d * DD + base) = cv.u;
}

extern "C" void kernel_launch(void* const* d_in, const int* in_sizes, int n_in,
                              void* d_out, int out_size, void* d_ws, size_t ws_size,
                              hipStream_t stream) {
    const float* x = (const float*)d_in[0];
    const int* edges[4] = {(const int*)d_in[1], (const int*)d_in[5], (const int*)d_in[9],
                           (const int*)d_in[13]};
    const float* W[4] = {(const float*)d_in[2], (const float*)d_in[6], (const float*)d_in[10],
                         (const float*)d_in[14]};
    const float* al[4] = {(const float*)d_in[3], (const float*)d_in[7], (const float*)d_in[11],
                          (const float*)d_in[15]};
    const float* ar[4] = {(const float*)d_in[4], (const float*)d_in[8], (const float*)d_in[12],
                          (const float*)d_in[16]};
    const float* Wl = (const float*)d_in[17];
    const float* bias = (const float*)d_in[18];
    float* out = (float*)d_out;

    char* w = (char*)d_ws;
    auto alloc = [&](size_t bytes) {
        char* p = w;
        w += (bytes + 255) & ~(size_t)255;
        return p;
    };
    __hip_bfloat16* x_bf = (__hip_bfloat16*)alloc((size_t)NN * DD * 2);
    __hip_bfloat16* h_bf = (__hip_bfloat16*)alloc((size_t)NN * DD * 2);
    __hip_bfloat16* t_bf = (__hip_bfloat16*)alloc((size_t)NN * DD * 2);
    __hip_bfloat16* xwl_bf = (__hip_bfloat16*)alloc((size_t)NN * DD * 2);
    __hip_bfloat16* Wt[4];
    for (int i = 0; i < 4; i++) Wt[i] = (__hip_bfloat16*)alloc((size_t)DD * DD * 2);
    __hip_bfloat16* WlTt = (__hip_bfloat16*)alloc((size_t)DD * DD * 2);
    __hip_bfloat16* WlTb = (__hip_bfloat16*)alloc((size_t)DD * DD * 2);
    float* el = (float*)alloc((size_t)NN * 4);
    float* er = (float*)alloc((size_t)NN * 4);
    int* deg4 = (int*)alloc((size_t)4 * NN * 4);
    int* rp4 = (int*)alloc((size_t)4 * (NN + 1) * 4);
    int* cur4 = (int*)alloc((size_t)4 * NN * 4);
    int* csr4 = (int*)alloc((size_t)4 * EE * 4);
    float* alpha_tmp = (float*)alloc((size_t)EE * 4);

    // preprocessing
    k_convert_bf16<<<(NN * DD / 4 + 255) / 256, 256, 0, stream>>>(x, x_bf, NN * DD / 4);
    dim3 tb(32, 32), tg(16, 16);
    for (int i = 0; i < 4; i++) k_transpose_bf16<<<tg, tb, 0, stream>>>(W[i], Wt[i]);
    k_transpose_bf16<<<tg, tb, 0, stream>>>(Wl, WlTt);
    k_transpose_bf16<<<tg, tb, 0, stream>>>(Wl + 512 * 512, WlTb);

    // CSR for all 4 relations (edges-only, hoisted)
    k_zero_i32<<<(4 * NN + 255) / 256, 256, 0, stream>>>(deg4, 4 * NN);
    k_count4<<<(4 * EE + 255) / 256, 256, 0, stream>>>(edges[0], edges[1], edges[2], edges[3], deg4);
    k_scan4<<<4, 1024, 0, stream>>>(deg4, rp4, cur4);
    k_scatter4<<<(4 * EE + 255) / 256, 256, 0, stream>>>(edges[0], edges[1], edges[2], edges[3],
                                                         cur4, csr4);

    dim3 gg((NN + 63) / 64, 2);
    // xwl = bf16(x @ Wl_top) (loop-invariant addend)
    k_gemm<<<gg, 256, 0, stream>>>(x_bf, WlTt, nullptr, xwl_bf, nullptr, NN, 0);

    for (int i = 0; i < 4; i++) {
        k_gemm<<<gg, 256, 0, stream>>>(x_bf, Wt[i], nullptr, h_bf, nullptr, NN, 0);
        k_el_er<<<NN / 4, 256, 0, stream>>>(h_bf, al[i], ar[i], el, er);
        k_agg_fused<<<(NN * 64 + 255) / 256, 256, 0, stream>>>(
            rp4 + i * (NN + 1), csr4 + (size_t)i * EE, el, er, h_bf, out, bias, t_bf, alpha_tmp,
            i > 0 ? 1 : 0);
        // out = relu(xwl + t @ Wl_bot)
        k_gemm<<<gg, 256, 0, stream>>>(t_bf, WlTb, out, nullptr, xwl_bf, NN, 1);
    }
}

// Round 6
// 917.612 us; speedup vs baseline: 1.0429x; 1.0429x over previous
//
#include <hip/hip_runtime.h>
#include <hip/hip_bf16.h>

#define NN 20000
#define DD 512
#define EE 150000

typedef __attribute__((ext_vector_type(8))) short short8;
typedef __attribute__((ext_vector_type(4))) float floatx4;

static __device__ __forceinline__ float bfbits2f(unsigned short u) {
    unsigned int x = ((unsigned int)u) << 16;
    return __uint_as_float(x);
}

#define GLOAD_LDS16(g, l)                                                        \
    __builtin_amdgcn_global_load_lds((const __attribute__((address_space(1))) void*)(g), \
                                     (__attribute__((address_space(3))) void*)(l), 16, 0, 0)

// ---------------- convert fp32 -> bf16 ----------------
__global__ __launch_bounds__(256) void k_convert_bf16(const float* __restrict__ in,
                                                      __hip_bfloat16* __restrict__ out, int n4) {
    int i = blockIdx.x * blockDim.x + threadIdx.x;
    if (i >= n4) return;
    float4 v = ((const float4*)in)[i];
    union { __hip_bfloat16 b[4]; ushort4 u; } cv;
    cv.b[0] = __float2bfloat16(v.x);
    cv.b[1] = __float2bfloat16(v.y);
    cv.b[2] = __float2bfloat16(v.z);
    cv.b[3] = __float2bfloat16(v.w);
    *(ushort4*)(out + 4l * i) = cv.u;
}

// ---------------- 512x512 transpose + convert to bf16 ----------------
__global__ __launch_bounds__(1024) void k_transpose_bf16(const float* __restrict__ in,
                                                         __hip_bfloat16* __restrict__ out) {
    __shared__ float tile[32][33];
    int bx = blockIdx.x * 32;
    int by = blockIdx.y * 32;
    int tx = threadIdx.x, ty = threadIdx.y;
    tile[ty][tx] = in[(by + ty) * 512 + bx + tx];
    __syncthreads();
    out[(bx + ty) * 512 + by + tx] = __float2bfloat16(tile[tx][ty]);
}

// ---------------- panel GEMM: C[32-row panel, 512] = A_panel @ B ----------------
// Block = 32 rows x FULL 512 cols (grid 625, 20000=625*32, no tail; A fetched
// from HBM exactly once -- no column-tile replication across XCDs).
// A panel (32 KB) staged to LDS once; K-loop has ZERO barriers (the per-phase
// vmcnt(0)+s_barrier drain was the structural limiter of rounds 1-4).
// Each wave owns 32x128: 8 B-frags/K-step direct global->VGPR (L2-hot,
// pipelined one K-step ahead, as in round 5) + 2 A-frags from LDS.
// Epilogue optionally computes el=h@al, er=h@ar (saves a 20MB-read kernel).
// mode 0: Cb = bf16(C). mode 1: Cf = relu(C + bf16 addend).
__global__ __launch_bounds__(256)
void k_gemm(const __hip_bfloat16* __restrict__ A, const __hip_bfloat16* __restrict__ Bt,
            float* __restrict__ Cf, __hip_bfloat16* __restrict__ Cb,
            const __hip_bfloat16* __restrict__ addend, const float* __restrict__ al,
            const float* __restrict__ ar, float* __restrict__ el, float* __restrict__ er,
            int mode) {
    __shared__ __hip_bfloat16 As[32 * 512];  // 32 KB; 16B-block i = [q=i>>5][row=i&31]
    __shared__ float elp[4][32], erp[4][32];
    const int tid = threadIdx.x;
    const int lane = tid & 63;
    const int wave = tid >> 6;
    const int row0 = blockIdx.x * 32;
    const int wcol0 = wave * 128;
    const int q8 = lane >> 4;
    const int l15 = lane & 15;

    // Stage A panel: thread t covers 16B-blocks t + j*256 (j=0..7)
    const __hip_bfloat16* aptr = A + (size_t)(row0 + (tid & 31)) * DD + (tid >> 5) * 8;
    __hip_bfloat16* alds = As + (size_t)tid * 8;
#pragma unroll
    for (int j = 0; j < 8; j++) GLOAD_LDS16(aptr + j * 64, alds + (size_t)j * 256 * 8);

    const __hip_bfloat16* bp[8];
#pragma unroll
    for (int ni = 0; ni < 8; ni++)
        bp[ni] = Bt + (size_t)(wcol0 + ni * 16 + l15) * DD + q8 * 8;

    floatx4 acc[2][8];
#pragma unroll
    for (int a = 0; a < 2; a++)
#pragma unroll
        for (int b = 0; b < 8; b++) acc[a][b] = (floatx4){0.f, 0.f, 0.f, 0.f};

    short8 bF[8];
#pragma unroll
    for (int ni = 0; ni < 8; ni++) bF[ni] = *(const short8*)bp[ni];
    __syncthreads();  // A panel resident; only barrier before epilogue

    for (int kb = 0; kb < 15; kb++) {
        short8 bN[8];
        const int ko = (kb + 1) * 32;
#pragma unroll
        for (int ni = 0; ni < 8; ni++) bN[ni] = *(const short8*)(bp[ni] + ko);
        short8 af[2];
#pragma unroll
        for (int mi = 0; mi < 2; mi++)
            af[mi] = *(const short8*)(As + ((size_t)(kb * 4 + q8) * 32 + mi * 16 + l15) * 8);
#pragma unroll
        for (int mi = 0; mi < 2; mi++)
#pragma unroll
            for (int ni = 0; ni < 8; ni++)
                acc[mi][ni] =
                    __builtin_amdgcn_mfma_f32_16x16x32_bf16(af[mi], bF[ni], acc[mi][ni], 0, 0, 0);
#pragma unroll
        for (int ni = 0; ni < 8; ni++) bF[ni] = bN[ni];
    }
    {
        short8 af[2];
#pragma unroll
        for (int mi = 0; mi < 2; mi++)
            af[mi] = *(const short8*)(As + ((size_t)(15 * 4 + q8) * 32 + mi * 16 + l15) * 8);
#pragma unroll
        for (int mi = 0; mi < 2; mi++)
#pragma unroll
            for (int ni = 0; ni < 8; ni++)
                acc[mi][ni] =
                    __builtin_amdgcn_mfma_f32_16x16x32_bf16(af[mi], bF[ni], acc[mi][ni], 0, 0, 0);
    }

    // ---- C write ----
#pragma unroll
    for (int mi = 0; mi < 2; mi++)
#pragma unroll
        for (int ni = 0; ni < 8; ni++)
#pragma unroll
            for (int r = 0; r < 4; r++) {
                int grow = row0 + mi * 16 + q8 * 4 + r;
                int gcol = wcol0 + ni * 16 + l15;
                float v = acc[mi][ni][r];
                size_t idx = (size_t)grow * DD + gcol;
                if (mode == 0) Cb[idx] = __float2bfloat16(v);
                else {
                    v += bfbits2f(*(const unsigned short*)(addend + idx));
                    Cf[idx] = v > 0.f ? v : 0.f;
                }
            }

    // ---- fused el/er (h @ al, h @ ar) ----
    if (al) {
        float alv[8], arv[8];
#pragma unroll
        for (int ni = 0; ni < 8; ni++) {
            alv[ni] = al[wcol0 + ni * 16 + l15];
            arv[ni] = ar[wcol0 + ni * 16 + l15];
        }
        float pel[8], per_[8];
#pragma unroll
        for (int mi = 0; mi < 2; mi++)
#pragma unroll
            for (int r = 0; r < 4; r++) {
                float sl = 0.f, sr = 0.f;
#pragma unroll
                for (int ni = 0; ni < 8; ni++) {
                    sl += acc[mi][ni][r] * alv[ni];
                    sr += acc[mi][ni][r] * arv[ni];
                }
                pel[mi * 4 + r] = sl;
                per_[mi * 4 + r] = sr;
            }
#pragma unroll
        for (int off = 1; off < 16; off <<= 1)
#pragma unroll
            for (int k = 0; k < 8; k++) {
                pel[k] += __shfl_xor(pel[k], off);
                per_[k] += __shfl_xor(per_[k], off);
            }
        if (l15 == 0) {
#pragma unroll
            for (int mi = 0; mi < 2; mi++)
#pragma unroll
                for (int r = 0; r < 4; r++) {
                    int row = mi * 16 + q8 * 4 + r;
                    elp[wave][row] = pel[mi * 4 + r];
                    erp[wave][row] = per_[mi * 4 + r];
                }
        }
        __syncthreads();
        if (tid < 32) {
            el[row0 + tid] = elp[0][tid] + elp[1][tid] + elp[2][tid] + elp[3][tid];
            er[row0 + tid] = erp[0][tid] + erp[1][tid] + erp[2][tid] + erp[3][tid];
        }
    }
}

// ---------------- CSR build (batched over 4 relations, hoisted pre-loop) ----------------
__global__ void k_zero_i32(int* p, int n) {
    int i = blockIdx.x * blockDim.x + threadIdx.x;
    if (i < n) p[i] = 0;
}

__global__ void k_count4(const int* __restrict__ e0, const int* __restrict__ e1,
                         const int* __restrict__ e2, const int* __restrict__ e3,
                         int* __restrict__ deg4) {
    int g = blockIdx.x * blockDim.x + threadIdx.x;
    if (g >= 4 * EE) return;
    int rel = g / EE;
    int e = g - rel * EE;
    const int* ed = rel == 0 ? e0 : rel == 1 ? e1 : rel == 2 ? e2 : e3;
    atomicAdd(&deg4[rel * NN + ed[EE + e]], 1);
}

__global__ __launch_bounds__(1024)
void k_scan4(const int* __restrict__ deg4, int* __restrict__ rp4, int* __restrict__ cur4) {
    const int rel = blockIdx.x;
    const int* deg = deg4 + rel * NN;
    int* row_ptr = rp4 + rel * (NN + 1);
    int* cursor = cur4 + rel * NN;
    __shared__ int sm[1024];
    int t = threadIdx.x;
    const int CH = 20;
    int begin = t * CH;
    int end = begin + CH;
    if (end > NN) end = NN;
    int s = 0;
    if (begin < NN)
        for (int i = begin; i < end; i++) s += deg[i];
    sm[t] = s;
    __syncthreads();
    for (int off = 1; off < 1024; off <<= 1) {
        int v = (t >= off) ? sm[t - off] : 0;
        __syncthreads();
        sm[t] += v;
        __syncthreads();
    }
    int run = sm[t] - s;
    if (begin < NN) {
        for (int i = begin; i < end; i++) {
            row_ptr[i] = run;
            cursor[i] = run;
            run += deg[i];
        }
        if (end == NN) row_ptr[NN] = run;
    }
}

__global__ void k_scatter4(const int* __restrict__ e0, const int* __restrict__ e1,
                           const int* __restrict__ e2, const int* __restrict__ e3,
                           int* __restrict__ cur4, int* __restrict__ csr4) {
    int g = blockIdx.x * blockDim.x + threadIdx.x;
    if (g >= 4 * EE) return;
    int rel = g / EE;
    int e = g - rel * EE;
    const int* ed = rel == 0 ? e0 : rel == 1 ? e1 : rel == 2 ? e2 : e3;
    int dst = ed[EE + e];
    int pos = atomicAdd(&cur4[rel * NN + dst], 1);
    csr4[rel * EE + pos] = ed[e];
}

// ---------------- fused edge-softmax + aggregate, wave per dst ----------------
__global__ __launch_bounds__(256)
void k_agg_fused(const int* __restrict__ row_ptr, const int* __restrict__ csr_src,
                 const float* __restrict__ el, const float* __restrict__ er,
                 const __hip_bfloat16* __restrict__ h, const float* __restrict__ out_prev,
                 const float* __restrict__ bias, __hip_bfloat16* __restrict__ t_out,
                 float* __restrict__ alpha_tmp, int use_prev) {
    int d = (blockIdx.x * blockDim.x + threadIdx.x) >> 6;
    int lane = threadIdx.x & 63;
    if (d >= NN) return;
    int s0 = row_ptr[d], s1 = row_ptr[d + 1];
    int deg = s1 - s0;
    int base = lane * 8;
    float acc[8] = {0.f, 0.f, 0.f, 0.f, 0.f, 0.f, 0.f, 0.f};

    if (deg <= 64) {
        int sv = 0;
        float av = 0.f;
        if (lane < deg) sv = csr_src[s0 + lane];
        float erd = er[d];
        float v = -1e30f;
        if (lane < deg) {
            float e = el[sv] + erd;
            v = e >= 0.f ? e : 0.2f * e;
        }
        float m = v;
#pragma unroll
        for (int off = 32; off > 0; off >>= 1) m = fmaxf(m, __shfl_xor(m, off));
        float wgt = (lane < deg) ? __expf(v - m) : 0.f;
        float s = wgt;
#pragma unroll
        for (int off = 32; off > 0; off >>= 1) s += __shfl_xor(s, off);
        av = wgt / s;
        int t = 0;
        for (; t + 1 < deg; t += 2) {
            int sA = __shfl(sv, t), sB = __shfl(sv, t + 1);
            float aA = __shfl(av, t), aB = __shfl(av, t + 1);
            uint4 hv0 = *(const uint4*)(h + (size_t)sA * DD + base);
            uint4 hv1 = *(const uint4*)(h + (size_t)sB * DD + base);
            const unsigned short* h0 = (const unsigned short*)&hv0;
            const unsigned short* h1 = (const unsigned short*)&hv1;
#pragma unroll
            for (int k = 0; k < 8; k++) acc[k] += aA * bfbits2f(h0[k]) + aB * bfbits2f(h1[k]);
        }
        if (t < deg) {
            int sA = __shfl(sv, t);
            float aA = __shfl(av, t);
            uint4 hv0 = *(const uint4*)(h + (size_t)sA * DD + base);
            const unsigned short* h0 = (const unsigned short*)&hv0;
#pragma unroll
            for (int k = 0; k < 8; k++) acc[k] += aA * bfbits2f(h0[k]);
        }
    } else {
        float erd = er[d];
        float m = -1e30f;
        for (int j = s0 + lane; j < s1; j += 64) {
            float e = el[csr_src[j]] + erd;
            e = e >= 0.f ? e : 0.2f * e;
            alpha_tmp[j] = e;
            m = fmaxf(m, e);
        }
#pragma unroll
        for (int off = 32; off > 0; off >>= 1) m = fmaxf(m, __shfl_xor(m, off));
        float s = 0.f;
        for (int j = s0 + lane; j < s1; j += 64) {
            float wv = __expf(alpha_tmp[j] - m);
            alpha_tmp[j] = wv;
            s += wv;
        }
#pragma unroll
        for (int off = 32; off > 0; off >>= 1) s += __shfl_xor(s, off);
        float inv = 1.f / s;
        for (int j0 = 0; j0 < deg; j0 += 64) {
            int cnt = deg - j0;
            if (cnt > 64) cnt = 64;
            int sv = 0;
            float av = 0.f;
            if (lane < cnt) {
                sv = csr_src[s0 + j0 + lane];
                av = alpha_tmp[s0 + j0 + lane] * inv;
            }
            for (int t = 0; t < cnt; t++) {
                int sA = __shfl(sv, t);
                float aA = __shfl(av, t);
                uint4 hv0 = *(const uint4*)(h + (size_t)sA * DD + base);
                const unsigned short* h0 = (const unsigned short*)&hv0;
#pragma unroll
                for (int k = 0; k < 8; k++) acc[k] += aA * bfbits2f(h0[k]);
            }
        }
    }

    if (use_prev) {
        float4 p0 = *(const float4*)(out_prev + (size_t)d * DD + base);
        float4 p1 = *(const float4*)(out_prev + (size_t)d * DD + base + 4);
        acc[0] += p0.x; acc[1] += p0.y; acc[2] += p0.z; acc[3] += p0.w;
        acc[4] += p1.x; acc[5] += p1.y; acc[6] += p1.z; acc[7] += p1.w;
    }
    float4 b0 = *(const float4*)(bias + base);
    float4 b1 = *(const float4*)(bias + base + 4);
    acc[0] += b0.x; acc[1] += b0.y; acc[2] += b0.z; acc[3] += b0.w;
    acc[4] += b1.x; acc[5] += b1.y; acc[6] += b1.z; acc[7] += b1.w;
    union { __hip_bfloat16 b[8]; uint4 u; } cv;
#pragma unroll
    for (int k = 0; k < 8; k++) cv.b[k] = __float2bfloat16(acc[k]);
    *(uint4*)(t_out + (size_t)d * DD + base) = cv.u;
}

extern "C" void kernel_launch(void* const* d_in, const int* in_sizes, int n_in,
                              void* d_out, int out_size, void* d_ws, size_t ws_size,
                              hipStream_t stream) {
    const float* x = (const float*)d_in[0];
    const int* edges[4] = {(const int*)d_in[1], (const int*)d_in[5], (const int*)d_in[9],
                           (const int*)d_in[13]};
    const float* W[4] = {(const float*)d_in[2], (const float*)d_in[6], (const float*)d_in[10],
                         (const float*)d_in[14]};
    const float* al[4] = {(const float*)d_in[3], (const float*)d_in[7], (const float*)d_in[11],
                          (const float*)d_in[15]};
    const float* ar[4] = {(const float*)d_in[4], (const float*)d_in[8], (const float*)d_in[12],
                          (const float*)d_in[16]};
    const float* Wl = (const float*)d_in[17];
    const float* bias = (const float*)d_in[18];
    float* out = (float*)d_out;

    char* w = (char*)d_ws;
    auto alloc = [&](size_t bytes) {
        char* p = w;
        w += (bytes + 255) & ~(size_t)255;
        return p;
    };
    __hip_bfloat16* x_bf = (__hip_bfloat16*)alloc((size_t)NN * DD * 2);
    __hip_bfloat16* h_bf = (__hip_bfloat16*)alloc((size_t)NN * DD * 2);
    __hip_bfloat16* t_bf = (__hip_bfloat16*)alloc((size_t)NN * DD * 2);
    __hip_bfloat16* xwl_bf = (__hip_bfloat16*)alloc((size_t)NN * DD * 2);
    __hip_bfloat16* Wt[4];
    for (int i = 0; i < 4; i++) Wt[i] = (__hip_bfloat16*)alloc((size_t)DD * DD * 2);
    __hip_bfloat16* WlTt = (__hip_bfloat16*)alloc((size_t)DD * DD * 2);
    __hip_bfloat16* WlTb = (__hip_bfloat16*)alloc((size_t)DD * DD * 2);
    float* el = (float*)alloc((size_t)NN * 4);
    float* er = (float*)alloc((size_t)NN * 4);
    int* deg4 = (int*)alloc((size_t)4 * NN * 4);
    int* rp4 = (int*)alloc((size_t)4 * (NN + 1) * 4);
    int* cur4 = (int*)alloc((size_t)4 * NN * 4);
    int* csr4 = (int*)alloc((size_t)4 * EE * 4);
    float* alpha_tmp = (float*)alloc((size_t)EE * 4);

    // preprocessing
    k_convert_bf16<<<(NN * DD / 4 + 255) / 256, 256, 0, stream>>>(x, x_bf, NN * DD / 4);
    dim3 tb(32, 32), tg(16, 16);
    for (int i = 0; i < 4; i++) k_transpose_bf16<<<tg, tb, 0, stream>>>(W[i], Wt[i]);
    k_transpose_bf16<<<tg, tb, 0, stream>>>(Wl, WlTt);
    k_transpose_bf16<<<tg, tb, 0, stream>>>(Wl + 512 * 512, WlTb);

    // CSR for all 4 relations (edges-only, hoisted)
    k_zero_i32<<<(4 * NN + 255) / 256, 256, 0, stream>>>(deg4, 4 * NN);
    k_count4<<<(4 * EE + 255) / 256, 256, 0, stream>>>(edges[0], edges[1], edges[2], edges[3], deg4);
    k_scan4<<<4, 1024, 0, stream>>>(deg4, rp4, cur4);
    k_scatter4<<<(4 * EE + 255) / 256, 256, 0, stream>>>(edges[0], edges[1], edges[2], edges[3],
                                                         cur4, csr4);

    const int GB = NN / 32;  // 625 blocks, exact
    // xwl = bf16(x @ Wl_top) (loop-invariant addend); no el/er
    k_gemm<<<GB, 256, 0, stream>>>(x_bf, WlTt, nullptr, xwl_bf, nullptr, nullptr, nullptr,
                                   nullptr, nullptr, 0);

    for (int i = 0; i < 4; i++) {
        // h = x @ W_i (bf16) + fused el/er
        k_gemm<<<GB, 256, 0, stream>>>(x_bf, Wt[i], nullptr, h_bf, nullptr, al[i], ar[i], el, er,
                                       0);
        k_agg_fused<<<(NN * 64 + 255) / 256, 256, 0, stream>>>(
            rp4 + i * (NN + 1), csr4 + (size_t)i * EE, el, er, h_bf, out, bias, t_bf, alpha_tmp,
            i > 0 ? 1 : 0);
        // out = relu(xwl + t @ Wl_bot)
        k_gemm<<<GB, 256, 0, stream>>>(t_bf, WlTb, out, nullptr, xwl_bf, nullptr, nullptr, nullptr,
                                       nullptr, 1);
    }
}

// Round 7
// 703.343 us; speedup vs baseline: 1.3607x; 1.3046x over previous
//
#include <hip/hip_runtime.h>
#include <hip/hip_bf16.h>

#define NN 20000
#define DD 512
#define EE 150000
#define NH 2560  // stacked GEMM width: 4*512 (W_i) + 512 (Wl_top)

typedef __attribute__((ext_vector_type(8))) short short8;
typedef __attribute__((ext_vector_type(4))) float floatx4;

static __device__ __forceinline__ float bfbits2f(unsigned short u) {
    unsigned int x = ((unsigned int)u) << 16;
    return __uint_as_float(x);
}

#define GLOAD_LDS16(g, l)                                                        \
    __builtin_amdgcn_global_load_lds((const __attribute__((address_space(1))) void*)(g), \
                                     (__attribute__((address_space(3))) void*)(l), 16, 0, 0)

// ---------------- convert fp32 -> bf16 ----------------
__global__ __launch_bounds__(256) void k_convert_bf16(const float* __restrict__ in,
                                                      __hip_bfloat16* __restrict__ out, int n4) {
    int i = blockIdx.x * blockDim.x + threadIdx.x;
    if (i >= n4) return;
    float4 v = ((const float4*)in)[i];
    union { __hip_bfloat16 b[4]; ushort4 u; } cv;
    cv.b[0] = __float2bfloat16(v.x);
    cv.b[1] = __float2bfloat16(v.y);
    cv.b[2] = __float2bfloat16(v.z);
    cv.b[3] = __float2bfloat16(v.w);
    *(ushort4*)(out + 4l * i) = cv.u;
}

// ---------------- 512x512 transpose + convert to bf16 ----------------
__global__ __launch_bounds__(1024) void k_transpose_bf16(const float* __restrict__ in,
                                                         __hip_bfloat16* __restrict__ out) {
    __shared__ float tile[32][33];
    int bx = blockIdx.x * 32;
    int by = blockIdx.y * 32;
    int tx = threadIdx.x, ty = threadIdx.y;
    tile[ty][tx] = in[(by + ty) * 512 + bx + tx];
    __syncthreads();
    out[(bx + ty) * 512 + by + tx] = __float2bfloat16(tile[tx][ty]);
}

// ---------------- bf16 MFMA GEMM: C[M, N] = A[M,512] @ B (Bt rows = N cols) ----
// Proven R3 tile (64 rows x 128 cols, glds staging, lane-linear LDS, 0 bank
// conflicts) upgraded to BK=64: 8 barrier-drain phases instead of 16 (the
// plateau's dominant stall term). 24 KB LDS -> ~6 blocks/CU.
// mode 0: Cb[grow*c_ld+gcol] = bf16(C).
// mode 1: Cf[grow*c_ld+gcol] = relu(C + bf16 addend[grow*add_ld + add_off + gcol]).
__global__ __launch_bounds__(256)
void k_gemm(const __hip_bfloat16* __restrict__ A, const __hip_bfloat16* __restrict__ Bt,
            float* __restrict__ Cf, __hip_bfloat16* __restrict__ Cb,
            const __hip_bfloat16* __restrict__ addend, int add_ld, int add_off, int c_ld,
            int M, int mode) {
    __shared__ __hip_bfloat16 As[64 * 64];    // 8 KB;  16B-block b = [q=b>>6][r=b&63]
    __shared__ __hip_bfloat16 Bs[128 * 64];   // 16 KB; 16B-block b = [q=b>>7][r=b&127]
    const int tid = threadIdx.x;
    const int lane = tid & 63;
    const int wave = tid >> 6;
    const int row0 = blockIdx.x * 64;
    const int col0 = blockIdx.y * 128;
    const int wm = (wave >> 1) * 32;
    const int wn = (wave & 1) * 64;
    const int q8 = lane >> 4;
    const int l15 = lane & 15;

    int ar_ = row0 + (tid & 63);
    if (ar_ >= M) ar_ = M - 1;
    const __hip_bfloat16* aptr = A + (size_t)ar_ * DD + (tid >> 6) * 8;  // q=tid>>6 (0..3)
    __hip_bfloat16* alds = As + (size_t)tid * 8;
    const __hip_bfloat16* bptr = Bt + (size_t)(col0 + (tid & 127)) * DD + (tid >> 7) * 8;
    __hip_bfloat16* blds = Bs + (size_t)tid * 8;

    floatx4 acc[2][4];
#pragma unroll
    for (int a = 0; a < 2; a++)
#pragma unroll
        for (int b = 0; b < 4; b++) acc[a][b] = (floatx4){0.f, 0.f, 0.f, 0.f};

    for (int k0 = 0; k0 < DD; k0 += 64) {
        __syncthreads();
        GLOAD_LDS16(aptr + k0, alds);                      // A q = tid>>6
        GLOAD_LDS16(aptr + k0 + 32, alds + 256 * 8);       // A q = (tid>>6)+4
#pragma unroll
        for (int j = 0; j < 4; j++)                        // B q = (tid>>7)+2j
            GLOAD_LDS16(bptr + k0 + j * 16, blds + (size_t)j * 256 * 8);
        __syncthreads();
#pragma unroll
        for (int kk = 0; kk < 2; kk++) {
            short8 af[2], bf[4];
#pragma unroll
            for (int mi = 0; mi < 2; mi++)
                af[mi] = *(const short8*)(As + ((size_t)(kk * 4 + q8) * 64 + wm + mi * 16 + l15) * 8);
#pragma unroll
            for (int ni = 0; ni < 4; ni++)
                bf[ni] = *(const short8*)(Bs + ((size_t)(kk * 4 + q8) * 128 + wn + ni * 16 + l15) * 8);
#pragma unroll
            for (int mi = 0; mi < 2; mi++)
#pragma unroll
                for (int ni = 0; ni < 4; ni++)
                    acc[mi][ni] =
                        __builtin_amdgcn_mfma_f32_16x16x32_bf16(af[mi], bf[ni], acc[mi][ni], 0, 0, 0);
        }
    }

#pragma unroll
    for (int mi = 0; mi < 2; mi++)
#pragma unroll
        for (int ni = 0; ni < 4; ni++)
#pragma unroll
            for (int r = 0; r < 4; r++) {
                int grow = row0 + wm + mi * 16 + q8 * 4 + r;
                int gcol = col0 + wn + ni * 16 + l15;
                if (grow < M) {
                    float v = acc[mi][ni][r];
                    if (mode == 0) {
                        Cb[(size_t)grow * c_ld + gcol] = __float2bfloat16(v);
                    } else {
                        v += bfbits2f(*(const unsigned short*)(addend + (size_t)grow * add_ld +
                                                               add_off + gcol));
                        Cf[(size_t)grow * c_ld + gcol] = v > 0.f ? v : 0.f;
                    }
                }
            }
}

// ---------------- el/er for all 4 relations in one pass over h_all ----------------
// block = 1 row, wave w handles relation w: el4[w*NN+row] = h_all[row, 512w:512w+512] . al_w
__global__ __launch_bounds__(256)
void k_el_er4(const __hip_bfloat16* __restrict__ h_all, const float* __restrict__ al0,
              const float* __restrict__ al1, const float* __restrict__ al2,
              const float* __restrict__ al3, const float* __restrict__ ar0,
              const float* __restrict__ ar1, const float* __restrict__ ar2,
              const float* __restrict__ ar3, float* __restrict__ el4, float* __restrict__ er4) {
    int row = blockIdx.x;
    int rel = threadIdx.x >> 6, lane = threadIdx.x & 63;
    const float* alp = rel == 0 ? al0 : rel == 1 ? al1 : rel == 2 ? al2 : al3;
    const float* arp = rel == 0 ? ar0 : rel == 1 ? ar1 : rel == 2 ? ar2 : ar3;
    uint4 hv = *(const uint4*)(h_all + (size_t)row * NH + rel * 512 + lane * 8);
    const unsigned short* hs = (const unsigned short*)&hv;
    float4 a0 = *(const float4*)(alp + lane * 8);
    float4 a1 = *(const float4*)(alp + lane * 8 + 4);
    float4 r0 = *(const float4*)(arp + lane * 8);
    float4 r1 = *(const float4*)(arp + lane * 8 + 4);
    float hf[8];
#pragma unroll
    for (int j = 0; j < 8; j++) hf[j] = bfbits2f(hs[j]);
    float sl = hf[0] * a0.x + hf[1] * a0.y + hf[2] * a0.z + hf[3] * a0.w +
               hf[4] * a1.x + hf[5] * a1.y + hf[6] * a1.z + hf[7] * a1.w;
    float sr = hf[0] * r0.x + hf[1] * r0.y + hf[2] * r0.z + hf[3] * r0.w +
               hf[4] * r1.x + hf[5] * r1.y + hf[6] * r1.z + hf[7] * r1.w;
#pragma unroll
    for (int off = 32; off > 0; off >>= 1) {
        sl += __shfl_down(sl, off);
        sr += __shfl_down(sr, off);
    }
    if (lane == 0) {
        el4[rel * NN + row] = sl;
        er4[rel * NN + row] = sr;
    }
}

// ---------------- CSR build (batched over 4 relations, hoisted pre-loop) ----------------
__global__ void k_zero_i32(int* p, int n) {
    int i = blockIdx.x * blockDim.x + threadIdx.x;
    if (i < n) p[i] = 0;
}

__global__ void k_count4(const int* __restrict__ e0, const int* __restrict__ e1,
                         const int* __restrict__ e2, const int* __restrict__ e3,
                         int* __restrict__ deg4) {
    int g = blockIdx.x * blockDim.x + threadIdx.x;
    if (g >= 4 * EE) return;
    int rel = g / EE;
    int e = g - rel * EE;
    const int* ed = rel == 0 ? e0 : rel == 1 ? e1 : rel == 2 ? e2 : e3;
    atomicAdd(&deg4[rel * NN + ed[EE + e]], 1);
}

__global__ __launch_bounds__(1024)
void k_scan4(const int* __restrict__ deg4, int* __restrict__ rp4, int* __restrict__ cur4) {
    const int rel = blockIdx.x;
    const int* deg = deg4 + rel * NN;
    int* row_ptr = rp4 + rel * (NN + 1);
    int* cursor = cur4 + rel * NN;
    __shared__ int sm[1024];
    int t = threadIdx.x;
    const int CH = 20;
    int begin = t * CH;
    int end = begin + CH;
    if (end > NN) end = NN;
    int s = 0;
    if (begin < NN)
        for (int i = begin; i < end; i++) s += deg[i];
    sm[t] = s;
    __syncthreads();
    for (int off = 1; off < 1024; off <<= 1) {
        int v = (t >= off) ? sm[t - off] : 0;
        __syncthreads();
        sm[t] += v;
        __syncthreads();
    }
    int run = sm[t] - s;
    if (begin < NN) {
        for (int i = begin; i < end; i++) {
            row_ptr[i] = run;
            cursor[i] = run;
            run += deg[i];
        }
        if (end == NN) row_ptr[NN] = run;
    }
}

__global__ void k_scatter4(const int* __restrict__ e0, const int* __restrict__ e1,
                           const int* __restrict__ e2, const int* __restrict__ e3,
                           int* __restrict__ cur4, int* __restrict__ csr4) {
    int g = blockIdx.x * blockDim.x + threadIdx.x;
    if (g >= 4 * EE) return;
    int rel = g / EE;
    int e = g - rel * EE;
    const int* ed = rel == 0 ? e0 : rel == 1 ? e1 : rel == 2 ? e2 : e3;
    int dst = ed[EE + e];
    int pos = atomicAdd(&cur4[rel * NN + dst], 1);
    csr4[rel * EE + pos] = ed[e];
}

// ---------------- fused edge-softmax + aggregate, wave per dst ----------------
// h has row-stride hs (h_all), base pointer pre-offset to the relation's column block.
__global__ __launch_bounds__(256)
void k_agg_fused(const int* __restrict__ row_ptr, const int* __restrict__ csr_src,
                 const float* __restrict__ el, const float* __restrict__ er,
                 const __hip_bfloat16* __restrict__ h, int hs,
                 const float* __restrict__ out_prev, const float* __restrict__ bias,
                 __hip_bfloat16* __restrict__ t_out, float* __restrict__ alpha_tmp,
                 int use_prev) {
    int d = (blockIdx.x * blockDim.x + threadIdx.x) >> 6;
    int lane = threadIdx.x & 63;
    if (d >= NN) return;
    int s0 = row_ptr[d], s1 = row_ptr[d + 1];
    int deg = s1 - s0;
    int base = lane * 8;
    float acc[8] = {0.f, 0.f, 0.f, 0.f, 0.f, 0.f, 0.f, 0.f};

    if (deg <= 64) {
        int sv = 0;
        float av = 0.f;
        if (lane < deg) sv = csr_src[s0 + lane];
        float erd = er[d];
        float v = -1e30f;
        if (lane < deg) {
            float e = el[sv] + erd;
            v = e >= 0.f ? e : 0.2f * e;
        }
        float m = v;
#pragma unroll
        for (int off = 32; off > 0; off >>= 1) m = fmaxf(m, __shfl_xor(m, off));
        float wgt = (lane < deg) ? __expf(v - m) : 0.f;
        float s = wgt;
#pragma unroll
        for (int off = 32; off > 0; off >>= 1) s += __shfl_xor(s, off);
        av = wgt / s;
        int t = 0;
        for (; t + 1 < deg; t += 2) {
            int sA = __shfl(sv, t), sB = __shfl(sv, t + 1);
            float aA = __shfl(av, t), aB = __shfl(av, t + 1);
            uint4 hv0 = *(const uint4*)(h + (size_t)sA * hs + base);
            uint4 hv1 = *(const uint4*)(h + (size_t)sB * hs + base);
            const unsigned short* h0 = (const unsigned short*)&hv0;
            const unsigned short* h1 = (const unsigned short*)&hv1;
#pragma unroll
            for (int k = 0; k < 8; k++) acc[k] += aA * bfbits2f(h0[k]) + aB * bfbits2f(h1[k]);
        }
        if (t < deg) {
            int sA = __shfl(sv, t);
            float aA = __shfl(av, t);
            uint4 hv0 = *(const uint4*)(h + (size_t)sA * hs + base);
            const unsigned short* h0 = (const unsigned short*)&hv0;
#pragma unroll
            for (int k = 0; k < 8; k++) acc[k] += aA * bfbits2f(h0[k]);
        }
    } else {
        float erd = er[d];
        float m = -1e30f;
        for (int j = s0 + lane; j < s1; j += 64) {
            float e = el[csr_src[j]] + erd;
            e = e >= 0.f ? e : 0.2f * e;
            alpha_tmp[j] = e;
            m = fmaxf(m, e);
        }
#pragma unroll
        for (int off = 32; off > 0; off >>= 1) m = fmaxf(m, __shfl_xor(m, off));
        float s = 0.f;
        for (int j = s0 + lane; j < s1; j += 64) {
            float wv = __expf(alpha_tmp[j] - m);
            alpha_tmp[j] = wv;
            s += wv;
        }
#pragma unroll
        for (int off = 32; off > 0; off >>= 1) s += __shfl_xor(s, off);
        float inv = 1.f / s;
        for (int j0 = 0; j0 < deg; j0 += 64) {
            int cnt = deg - j0;
            if (cnt > 64) cnt = 64;
            int sv = 0;
            float av = 0.f;
            if (lane < cnt) {
                sv = csr_src[s0 + j0 + lane];
                av = alpha_tmp[s0 + j0 + lane] * inv;
            }
            for (int t = 0; t < cnt; t++) {
                int sA = __shfl(sv, t);
                float aA = __shfl(av, t);
                uint4 hv0 = *(const uint4*)(h + (size_t)sA * hs + base);
                const unsigned short* h0 = (const unsigned short*)&hv0;
#pragma unroll
                for (int k = 0; k < 8; k++) acc[k] += aA * bfbits2f(h0[k]);
            }
        }
    }

    if (use_prev) {
        float4 p0 = *(const float4*)(out_prev + (size_t)d * DD + base);
        float4 p1 = *(const float4*)(out_prev + (size_t)d * DD + base + 4);
        acc[0] += p0.x; acc[1] += p0.y; acc[2] += p0.z; acc[3] += p0.w;
        acc[4] += p1.x; acc[5] += p1.y; acc[6] += p1.z; acc[7] += p1.w;
    }
    float4 b0 = *(const float4*)(bias + base);
    float4 b1 = *(const float4*)(bias + base + 4);
    acc[0] += b0.x; acc[1] += b0.y; acc[2] += b0.z; acc[3] += b0.w;
    acc[4] += b1.x; acc[5] += b1.y; acc[6] += b1.z; acc[7] += b1.w;
    union { __hip_bfloat16 b[8]; uint4 u; } cv;
#pragma unroll
    for (int k = 0; k < 8; k++) cv.b[k] = __float2bfloat16(acc[k]);
    *(uint4*)(t_out + (size_t)d * DD + base) = cv.u;
}

extern "C" void kernel_launch(void* const* d_in, const int* in_sizes, int n_in,
                              void* d_out, int out_size, void* d_ws, size_t ws_size,
                              hipStream_t stream) {
    const float* x = (const float*)d_in[0];
    const int* edges[4] = {(const int*)d_in[1], (const int*)d_in[5], (const int*)d_in[9],
                           (const int*)d_in[13]};
    const float* W[4] = {(const float*)d_in[2], (const float*)d_in[6], (const float*)d_in[10],
                         (const float*)d_in[14]};
    const float* al[4] = {(const float*)d_in[3], (const float*)d_in[7], (const float*)d_in[11],
                          (const float*)d_in[15]};
    const float* ar[4] = {(const float*)d_in[4], (const float*)d_in[8], (const float*)d_in[12],
                          (const float*)d_in[16]};
    const float* Wl = (const float*)d_in[17];
    const float* bias = (const float*)d_in[18];
    float* out = (float*)d_out;

    char* w = (char*)d_ws;
    auto alloc = [&](size_t bytes) {
        char* p = w;
        w += (bytes + 255) & ~(size_t)255;
        return p;
    };
    __hip_bfloat16* x_bf = (__hip_bfloat16*)alloc((size_t)NN * DD * 2);
    __hip_bfloat16* h_all = (__hip_bfloat16*)alloc((size_t)NN * NH * 2);  // [h0|h1|h2|h3|xwl]
    __hip_bfloat16* t_bf = (__hip_bfloat16*)alloc((size_t)NN * DD * 2);
    __hip_bfloat16* Bt_all = (__hip_bfloat16*)alloc((size_t)NH * DD * 2);  // [W0..W3,WlTop]^T
    __hip_bfloat16* WlTb = (__hip_bfloat16*)alloc((size_t)DD * DD * 2);
    float* el4 = (float*)alloc((size_t)4 * NN * 4);
    float* er4 = (float*)alloc((size_t)4 * NN * 4);
    int* deg4 = (int*)alloc((size_t)4 * NN * 4);
    int* rp4 = (int*)alloc((size_t)4 * (NN + 1) * 4);
    int* cur4 = (int*)alloc((size_t)4 * NN * 4);
    int* csr4 = (int*)alloc((size_t)4 * EE * 4);
    float* alpha_tmp = (float*)alloc((size_t)EE * 4);

    // preprocessing
    k_convert_bf16<<<(NN * DD / 4 + 255) / 256, 256, 0, stream>>>(x, x_bf, NN * DD / 4);
    dim3 tb(32, 32), tg(16, 16);
    for (int i = 0; i < 4; i++)
        k_transpose_bf16<<<tg, tb, 0, stream>>>(W[i], Bt_all + (size_t)i * DD * DD);
    k_transpose_bf16<<<tg, tb, 0, stream>>>(Wl, Bt_all + (size_t)4 * DD * DD);
    k_transpose_bf16<<<tg, tb, 0, stream>>>(Wl + DD * DD, WlTb);

    // CSR for all 4 relations (edges-only, hoisted)
    k_zero_i32<<<(4 * NN + 255) / 256, 256, 0, stream>>>(deg4, 4 * NN);
    k_count4<<<(4 * EE + 255) / 256, 256, 0, stream>>>(edges[0], edges[1], edges[2], edges[3], deg4);
    k_scan4<<<4, 1024, 0, stream>>>(deg4, rp4, cur4);
    k_scatter4<<<(4 * EE + 255) / 256, 256, 0, stream>>>(edges[0], edges[1], edges[2], edges[3],
                                                         cur4, csr4);

    // MEGA-GEMM: h_all[NN, 2560] = x @ [W0|W1|W2|W3|Wl_top]
    dim3 gg1((NN + 63) / 64, NH / 128);
    k_gemm<<<gg1, 256, 0, stream>>>(x_bf, Bt_all, nullptr, h_all, nullptr, 0, 0, NH, NN, 0);

    // el/er all 4 relations, one pass
    k_el_er4<<<NN, 256, 0, stream>>>(h_all, al[0], al[1], al[2], al[3], ar[0], ar[1], ar[2], ar[3],
                                     el4, er4);

    dim3 gg2((NN + 63) / 64, DD / 128);
    for (int i = 0; i < 4; i++) {
        k_agg_fused<<<(NN * 64 + 255) / 256, 256, 0, stream>>>(
            rp4 + i * (NN + 1), csr4 + (size_t)i * EE, el4 + i * NN, er4 + i * NN,
            h_all + (size_t)i * 512, NH, out, bias, t_bf, alpha_tmp, i > 0 ? 1 : 0);
        // out = relu(xwl + t @ Wl_bot); xwl lives at h_all cols [2048,2560)
        k_gemm<<<gg2, 256, 0, stream>>>(t_bf, WlTb, out, nullptr, h_all, NH, 2048, DD, NN, 1);
    }
}

// Round 8
// 687.663 us; speedup vs baseline: 1.3917x; 1.0228x over previous
//
#include <hip/hip_runtime.h>
#include <hip/hip_bf16.h>

#define NN 20000
#define DD 512
#define EE 150000
#define NH 2560  // stacked GEMM width: 4*512 (W_i) + 512 (Wl_top)

typedef __attribute__((ext_vector_type(8))) short short8;
typedef __attribute__((ext_vector_type(4))) float floatx4;

static __device__ __forceinline__ float bfbits2f(unsigned short u) {
    unsigned int x = ((unsigned int)u) << 16;
    return __uint_as_float(x);
}

#define GLOAD_LDS16(g, l)                                                        \
    __builtin_amdgcn_global_load_lds((const __attribute__((address_space(1))) void*)(g), \
                                     (__attribute__((address_space(3))) void*)(l), 16, 0, 0)

// ---------------- convert fp32 -> bf16 ----------------
__global__ __launch_bounds__(256) void k_convert_bf16(const float* __restrict__ in,
                                                      __hip_bfloat16* __restrict__ out, int n4) {
    int i = blockIdx.x * blockDim.x + threadIdx.x;
    if (i >= n4) return;
    float4 v = ((const float4*)in)[i];
    union { __hip_bfloat16 b[4]; ushort4 u; } cv;
    cv.b[0] = __float2bfloat16(v.x);
    cv.b[1] = __float2bfloat16(v.y);
    cv.b[2] = __float2bfloat16(v.z);
    cv.b[3] = __float2bfloat16(v.w);
    *(ushort4*)(out + 4l * i) = cv.u;
}

// ---------------- 512x512 transpose + convert to bf16 ----------------
__global__ __launch_bounds__(1024) void k_transpose_bf16(const float* __restrict__ in,
                                                         __hip_bfloat16* __restrict__ out) {
    __shared__ float tile[32][33];
    int bx = blockIdx.x * 32;
    int by = blockIdx.y * 32;
    int tx = threadIdx.x, ty = threadIdx.y;
    tile[ty][tx] = in[(by + ty) * 512 + bx + tx];
    __syncthreads();
    out[(bx + ty) * 512 + by + tx] = __float2bfloat16(tile[tx][ty]);
}

// ---------------- bf16 MFMA GEMM: C[M, N] = A[M,512] @ B (Bt rows = N cols) ----
// 64x128 tile, BK=64, glds staging (0 bank conflicts, verified R2-R7).
// XCD-locality swizzle: R7 mega showed FETCH 212MB vs 25MB compulsory --
// col-tiles of a row-panel land round-robin on 8 XCD L2s, each re-fetching
// the A panel. Remap linear block id so all CT col-tiles of a row-panel share
// lin%8 (same XCD heuristic) and are dispatch-adjacent: A panel (65KB) served
// from that XCD's L2 after first touch.
// mode 0: Cb = bf16(C). mode 1: Cf = relu(C + bf16 addend) fp32.
// mode 2: Cb = bf16(relu(C + bf16 addend)).
__global__ __launch_bounds__(256)
void k_gemm(const __hip_bfloat16* __restrict__ A, const __hip_bfloat16* __restrict__ Bt,
            float* __restrict__ Cf, __hip_bfloat16* __restrict__ Cb,
            const __hip_bfloat16* __restrict__ addend, int add_ld, int add_off, int c_ld,
            int M, int CT, int mode) {
    const int RT = (M + 63) >> 6;
    const int xcd = blockIdx.x & 7;
    const int k_ = blockIdx.x >> 3;
    const int ctile = k_ % CT;
    const int rtile = (k_ / CT) * 8 + xcd;
    if (rtile >= RT) return;

    __shared__ __hip_bfloat16 As[64 * 64];    // 8 KB;  16B-block b = [q=b>>6][r=b&63]
    __shared__ __hip_bfloat16 Bs[128 * 64];   // 16 KB; 16B-block b = [q=b>>7][r=b&127]
    const int tid = threadIdx.x;
    const int lane = tid & 63;
    const int wave = tid >> 6;
    const int row0 = rtile * 64;
    const int col0 = ctile * 128;
    const int wm = (wave >> 1) * 32;
    const int wn = (wave & 1) * 64;
    const int q8 = lane >> 4;
    const int l15 = lane & 15;

    int ar_ = row0 + (tid & 63);
    if (ar_ >= M) ar_ = M - 1;
    const __hip_bfloat16* aptr = A + (size_t)ar_ * DD + (tid >> 6) * 8;
    __hip_bfloat16* alds = As + (size_t)tid * 8;
    const __hip_bfloat16* bptr = Bt + (size_t)(col0 + (tid & 127)) * DD + (tid >> 7) * 8;
    __hip_bfloat16* blds = Bs + (size_t)tid * 8;

    floatx4 acc[2][4];
#pragma unroll
    for (int a = 0; a < 2; a++)
#pragma unroll
        for (int b = 0; b < 4; b++) acc[a][b] = (floatx4){0.f, 0.f, 0.f, 0.f};

    for (int k0 = 0; k0 < DD; k0 += 64) {
        __syncthreads();
        GLOAD_LDS16(aptr + k0, alds);
        GLOAD_LDS16(aptr + k0 + 32, alds + 256 * 8);
#pragma unroll
        for (int j = 0; j < 4; j++)
            GLOAD_LDS16(bptr + k0 + j * 16, blds + (size_t)j * 256 * 8);
        __syncthreads();
#pragma unroll
        for (int kk = 0; kk < 2; kk++) {
            short8 af[2], bf[4];
#pragma unroll
            for (int mi = 0; mi < 2; mi++)
                af[mi] = *(const short8*)(As + ((size_t)(kk * 4 + q8) * 64 + wm + mi * 16 + l15) * 8);
#pragma unroll
            for (int ni = 0; ni < 4; ni++)
                bf[ni] = *(const short8*)(Bs + ((size_t)(kk * 4 + q8) * 128 + wn + ni * 16 + l15) * 8);
#pragma unroll
            for (int mi = 0; mi < 2; mi++)
#pragma unroll
                for (int ni = 0; ni < 4; ni++)
                    acc[mi][ni] =
                        __builtin_amdgcn_mfma_f32_16x16x32_bf16(af[mi], bf[ni], acc[mi][ni], 0, 0, 0);
        }
    }

#pragma unroll
    for (int mi = 0; mi < 2; mi++)
#pragma unroll
        for (int ni = 0; ni < 4; ni++)
#pragma unroll
            for (int r = 0; r < 4; r++) {
                int grow = row0 + wm + mi * 16 + q8 * 4 + r;
                int gcol = col0 + wn + ni * 16 + l15;
                if (grow < M) {
                    float v = acc[mi][ni][r];
                    if (mode == 0) {
                        Cb[(size_t)grow * c_ld + gcol] = __float2bfloat16(v);
                    } else {
                        v += bfbits2f(*(const unsigned short*)(addend + (size_t)grow * add_ld +
                                                               add_off + gcol));
                        v = v > 0.f ? v : 0.f;
                        if (mode == 1) Cf[(size_t)grow * c_ld + gcol] = v;
                        else Cb[(size_t)grow * c_ld + gcol] = __float2bfloat16(v);
                    }
                }
            }
}

// ---------------- el/er for all 4 relations in one pass over h_all ----------------
__global__ __launch_bounds__(256)
void k_el_er4(const __hip_bfloat16* __restrict__ h_all, const float* __restrict__ al0,
              const float* __restrict__ al1, const float* __restrict__ al2,
              const float* __restrict__ al3, const float* __restrict__ ar0,
              const float* __restrict__ ar1, const float* __restrict__ ar2,
              const float* __restrict__ ar3, float* __restrict__ el4, float* __restrict__ er4) {
    int row = blockIdx.x;
    int rel = threadIdx.x >> 6, lane = threadIdx.x & 63;
    const float* alp = rel == 0 ? al0 : rel == 1 ? al1 : rel == 2 ? al2 : al3;
    const float* arp = rel == 0 ? ar0 : rel == 1 ? ar1 : rel == 2 ? ar2 : ar3;
    uint4 hv = *(const uint4*)(h_all + (size_t)row * NH + rel * 512 + lane * 8);
    const unsigned short* hs = (const unsigned short*)&hv;
    float4 a0 = *(const float4*)(alp + lane * 8);
    float4 a1 = *(const float4*)(alp + lane * 8 + 4);
    float4 r0 = *(const float4*)(arp + lane * 8);
    float4 r1 = *(const float4*)(arp + lane * 8 + 4);
    float hf[8];
#pragma unroll
    for (int j = 0; j < 8; j++) hf[j] = bfbits2f(hs[j]);
    float sl = hf[0] * a0.x + hf[1] * a0.y + hf[2] * a0.z + hf[3] * a0.w +
               hf[4] * a1.x + hf[5] * a1.y + hf[6] * a1.z + hf[7] * a1.w;
    float sr = hf[0] * r0.x + hf[1] * r0.y + hf[2] * r0.z + hf[3] * r0.w +
               hf[4] * r1.x + hf[5] * r1.y + hf[6] * r1.z + hf[7] * r1.w;
#pragma unroll
    for (int off = 32; off > 0; off >>= 1) {
        sl += __shfl_down(sl, off);
        sr += __shfl_down(sr, off);
    }
    if (lane == 0) {
        el4[rel * NN + row] = sl;
        er4[rel * NN + row] = sr;
    }
}

// ---------------- CSR build (batched over 4 relations, hoisted pre-loop) ----------------
__global__ void k_zero_i32(int* p, int n) {
    int i = blockIdx.x * blockDim.x + threadIdx.x;
    if (i < n) p[i] = 0;
}

__global__ void k_count4(const int* __restrict__ e0, const int* __restrict__ e1,
                         const int* __restrict__ e2, const int* __restrict__ e3,
                         int* __restrict__ deg4) {
    int g = blockIdx.x * blockDim.x + threadIdx.x;
    if (g >= 4 * EE) return;
    int rel = g / EE;
    int e = g - rel * EE;
    const int* ed = rel == 0 ? e0 : rel == 1 ? e1 : rel == 2 ? e2 : e3;
    atomicAdd(&deg4[rel * NN + ed[EE + e]], 1);
}

__global__ __launch_bounds__(1024)
void k_scan4(const int* __restrict__ deg4, int* __restrict__ rp4, int* __restrict__ cur4) {
    const int rel = blockIdx.x;
    const int* deg = deg4 + rel * NN;
    int* row_ptr = rp4 + rel * (NN + 1);
    int* cursor = cur4 + rel * NN;
    __shared__ int sm[1024];
    int t = threadIdx.x;
    const int CH = 20;
    int begin = t * CH;
    int end = begin + CH;
    if (end > NN) end = NN;
    int s = 0;
    if (begin < NN)
        for (int i = begin; i < end; i++) s += deg[i];
    sm[t] = s;
    __syncthreads();
    for (int off = 1; off < 1024; off <<= 1) {
        int v = (t >= off) ? sm[t - off] : 0;
        __syncthreads();
        sm[t] += v;
        __syncthreads();
    }
    int run = sm[t] - s;
    if (begin < NN) {
        for (int i = begin; i < end; i++) {
            row_ptr[i] = run;
            cursor[i] = run;
            run += deg[i];
        }
        if (end == NN) row_ptr[NN] = run;
    }
}

__global__ void k_scatter4(const int* __restrict__ e0, const int* __restrict__ e1,
                           const int* __restrict__ e2, const int* __restrict__ e3,
                           int* __restrict__ cur4, int* __restrict__ csr4) {
    int g = blockIdx.x * blockDim.x + threadIdx.x;
    if (g >= 4 * EE) return;
    int rel = g / EE;
    int e = g - rel * EE;
    const int* ed = rel == 0 ? e0 : rel == 1 ? e1 : rel == 2 ? e2 : e3;
    int dst = ed[EE + e];
    int pos = atomicAdd(&cur4[rel * NN + dst], 1);
    csr4[rel * EE + pos] = ed[e];
}

// ---------------- fused edge-softmax + aggregate, wave per dst ----------------
// out_prev is bf16 (intermediate `out` stored bf16; one extra rounding, within margin)
__global__ __launch_bounds__(256)
void k_agg_fused(const int* __restrict__ row_ptr, const int* __restrict__ csr_src,
                 const float* __restrict__ el, const float* __restrict__ er,
                 const __hip_bfloat16* __restrict__ h, int hs,
                 const __hip_bfloat16* __restrict__ out_prev, const float* __restrict__ bias,
                 __hip_bfloat16* __restrict__ t_out, float* __restrict__ alpha_tmp,
                 int use_prev) {
    int d = (blockIdx.x * blockDim.x + threadIdx.x) >> 6;
    int lane = threadIdx.x & 63;
    if (d >= NN) return;
    int s0 = row_ptr[d], s1 = row_ptr[d + 1];
    int deg = s1 - s0;
    int base = lane * 8;
    float acc[8] = {0.f, 0.f, 0.f, 0.f, 0.f, 0.f, 0.f, 0.f};

    if (deg <= 64) {
        int sv = 0;
        float av = 0.f;
        if (lane < deg) sv = csr_src[s0 + lane];
        float erd = er[d];
        float v = -1e30f;
        if (lane < deg) {
            float e = el[sv] + erd;
            v = e >= 0.f ? e : 0.2f * e;
        }
        float m = v;
#pragma unroll
        for (int off = 32; off > 0; off >>= 1) m = fmaxf(m, __shfl_xor(m, off));
        float wgt = (lane < deg) ? __expf(v - m) : 0.f;
        float s = wgt;
#pragma unroll
        for (int off = 32; off > 0; off >>= 1) s += __shfl_xor(s, off);
        av = wgt / s;
        int t = 0;
        for (; t + 1 < deg; t += 2) {
            int sA = __shfl(sv, t), sB = __shfl(sv, t + 1);
            float aA = __shfl(av, t), aB = __shfl(av, t + 1);
            uint4 hv0 = *(const uint4*)(h + (size_t)sA * hs + base);
            uint4 hv1 = *(const uint4*)(h + (size_t)sB * hs + base);
            const unsigned short* h0 = (const unsigned short*)&hv0;
            const unsigned short* h1 = (const unsigned short*)&hv1;
#pragma unroll
            for (int k = 0; k < 8; k++) acc[k] += aA * bfbits2f(h0[k]) + aB * bfbits2f(h1[k]);
        }
        if (t < deg) {
            int sA = __shfl(sv, t);
            float aA = __shfl(av, t);
            uint4 hv0 = *(const uint4*)(h + (size_t)sA * hs + base);
            const unsigned short* h0 = (const unsigned short*)&hv0;
#pragma unroll
            for (int k = 0; k < 8; k++) acc[k] += aA * bfbits2f(h0[k]);
        }
    } else {
        float erd = er[d];
        float m = -1e30f;
        for (int j = s0 + lane; j < s1; j += 64) {
            float e = el[csr_src[j]] + erd;
            e = e >= 0.f ? e : 0.2f * e;
            alpha_tmp[j] = e;
            m = fmaxf(m, e);
        }
#pragma unroll
        for (int off = 32; off > 0; off >>= 1) m = fmaxf(m, __shfl_xor(m, off));
        float s = 0.f;
        for (int j = s0 + lane; j < s1; j += 64) {
            float wv = __expf(alpha_tmp[j] - m);
            alpha_tmp[j] = wv;
            s += wv;
        }
#pragma unroll
        for (int off = 32; off > 0; off >>= 1) s += __shfl_xor(s, off);
        float inv = 1.f / s;
        for (int j0 = 0; j0 < deg; j0 += 64) {
            int cnt = deg - j0;
            if (cnt > 64) cnt = 64;
            int sv = 0;
            float av = 0.f;
            if (lane < cnt) {
                sv = csr_src[s0 + j0 + lane];
                av = alpha_tmp[s0 + j0 + lane] * inv;
            }
            for (int t = 0; t < cnt; t++) {
                int sA = __shfl(sv, t);
                float aA = __shfl(av, t);
                uint4 hv0 = *(const uint4*)(h + (size_t)sA * hs + base);
                const unsigned short* h0 = (const unsigned short*)&hv0;
#pragma unroll
                for (int k = 0; k < 8; k++) acc[k] += aA * bfbits2f(h0[k]);
            }
        }
    }

    if (use_prev) {
        uint4 pv = *(const uint4*)(out_prev + (size_t)d * DD + base);
        const unsigned short* pp = (const unsigned short*)&pv;
#pragma unroll
        for (int k = 0; k < 8; k++) acc[k] += bfbits2f(pp[k]);
    }
    float4 b0 = *(const float4*)(bias + base);
    float4 b1 = *(const float4*)(bias + base + 4);
    acc[0] += b0.x; acc[1] += b0.y; acc[2] += b0.z; acc[3] += b0.w;
    acc[4] += b1.x; acc[5] += b1.y; acc[6] += b1.z; acc[7] += b1.w;
    union { __hip_bfloat16 b[8]; uint4 u; } cv;
#pragma unroll
    for (int k = 0; k < 8; k++) cv.b[k] = __float2bfloat16(acc[k]);
    *(uint4*)(t_out + (size_t)d * DD + base) = cv.u;
}

extern "C" void kernel_launch(void* const* d_in, const int* in_sizes, int n_in,
                              void* d_out, int out_size, void* d_ws, size_t ws_size,
                              hipStream_t stream) {
    const float* x = (const float*)d_in[0];
    const int* edges[4] = {(const int*)d_in[1], (const int*)d_in[5], (const int*)d_in[9],
                           (const int*)d_in[13]};
    const float* W[4] = {(const float*)d_in[2], (const float*)d_in[6], (const float*)d_in[10],
                         (const float*)d_in[14]};
    const float* al[4] = {(const float*)d_in[3], (const float*)d_in[7], (const float*)d_in[11],
                          (const float*)d_in[15]};
    const float* ar[4] = {(const float*)d_in[4], (const float*)d_in[8], (const float*)d_in[12],
                          (const float*)d_in[16]};
    const float* Wl = (const float*)d_in[17];
    const float* bias = (const float*)d_in[18];
    float* out = (float*)d_out;

    char* w = (char*)d_ws;
    auto alloc = [&](size_t bytes) {
        char* p = w;
        w += (bytes + 255) & ~(size_t)255;
        return p;
    };
    __hip_bfloat16* x_bf = (__hip_bfloat16*)alloc((size_t)NN * DD * 2);
    __hip_bfloat16* h_all = (__hip_bfloat16*)alloc((size_t)NN * NH * 2);  // [h0|h1|h2|h3|xwl]
    __hip_bfloat16* t_bf = (__hip_bfloat16*)alloc((size_t)NN * DD * 2);
    __hip_bfloat16* out_bf = (__hip_bfloat16*)alloc((size_t)NN * DD * 2);  // intermediate out
    __hip_bfloat16* Bt_all = (__hip_bfloat16*)alloc((size_t)NH * DD * 2);  // [W0..W3,WlTop]^T
    __hip_bfloat16* WlTb = (__hip_bfloat16*)alloc((size_t)DD * DD * 2);
    float* el4 = (float*)alloc((size_t)4 * NN * 4);
    float* er4 = (float*)alloc((size_t)4 * NN * 4);
    int* deg4 = (int*)alloc((size_t)4 * NN * 4);
    int* rp4 = (int*)alloc((size_t)4 * (NN + 1) * 4);
    int* cur4 = (int*)alloc((size_t)4 * NN * 4);
    int* csr4 = (int*)alloc((size_t)4 * EE * 4);
    float* alpha_tmp = (float*)alloc((size_t)EE * 4);

    // preprocessing
    k_convert_bf16<<<(NN * DD / 4 + 255) / 256, 256, 0, stream>>>(x, x_bf, NN * DD / 4);
    dim3 tb(32, 32), tg(16, 16);
    for (int i = 0; i < 4; i++)
        k_transpose_bf16<<<tg, tb, 0, stream>>>(W[i], Bt_all + (size_t)i * DD * DD);
    k_transpose_bf16<<<tg, tb, 0, stream>>>(Wl, Bt_all + (size_t)4 * DD * DD);
    k_transpose_bf16<<<tg, tb, 0, stream>>>(Wl + DD * DD, WlTb);

    // CSR for all 4 relations (edges-only, hoisted)
    k_zero_i32<<<(4 * NN + 255) / 256, 256, 0, stream>>>(deg4, 4 * NN);
    k_count4<<<(4 * EE + 255) / 256, 256, 0, stream>>>(edges[0], edges[1], edges[2], edges[3], deg4);
    k_scan4<<<4, 1024, 0, stream>>>(deg4, rp4, cur4);
    k_scatter4<<<(4 * EE + 255) / 256, 256, 0, stream>>>(edges[0], edges[1], edges[2], edges[3],
                                                         cur4, csr4);

    const int RT = (NN + 63) / 64;          // 313
    const int RTp8 = ((RT + 7) / 8) * 8;    // 320
    // MEGA-GEMM: h_all[NN, 2560] = x @ [W0|W1|W2|W3|Wl_top]; CT=20
    k_gemm<<<RTp8 * 20, 256, 0, stream>>>(x_bf, Bt_all, nullptr, h_all, nullptr, 0, 0, NH, NN, 20,
                                          0);

    // el/er all 4 relations, one pass
    k_el_er4<<<NN, 256, 0, stream>>>(h_all, al[0], al[1], al[2], al[3], ar[0], ar[1], ar[2], ar[3],
                                     el4, er4);

    for (int i = 0; i < 4; i++) {
        k_agg_fused<<<(NN * 64 + 255) / 256, 256, 0, stream>>>(
            rp4 + i * (NN + 1), csr4 + (size_t)i * EE, el4 + i * NN, er4 + i * NN,
            h_all + (size_t)i * 512, NH, out_bf, bias, t_bf, alpha_tmp, i > 0 ? 1 : 0);
        // out = relu(xwl + t @ Wl_bot); xwl at h_all cols [2048,2560). CT=4.
        // i<3 -> bf16 scratch (mode 2); i=3 -> fp32 d_out (mode 1)
        if (i < 3)
            k_gemm<<<RTp8 * 4, 256, 0, stream>>>(t_bf, WlTb, nullptr, out_bf, h_all, NH, 2048, DD,
                                                 NN, 4, 2);
        else
            k_gemm<<<RTp8 * 4, 256, 0, stream>>>(t_bf, WlTb, out, nullptr, h_all, NH, 2048, DD,
                                                 NN, 4, 1);
    }
}

// Round 9
// 674.364 us; speedup vs baseline: 1.4191x; 1.0197x over previous
//
#include <hip/hip_runtime.h>
#include <hip/hip_bf16.h>

#define NN 20000
#define DD 512
#define EE 150000
#define NH 2560  // stacked GEMM width: 4*512 (W_i) + 512 (Wl_top)

typedef __attribute__((ext_vector_type(8))) short short8;
typedef __attribute__((ext_vector_type(4))) float floatx4;

static __device__ __forceinline__ float bfbits2f(unsigned short u) {
    unsigned int x = ((unsigned int)u) << 16;
    return __uint_as_float(x);
}

#define GLOAD_LDS16(g, l)                                                        \
    __builtin_amdgcn_global_load_lds((const __attribute__((address_space(1))) void*)(g), \
                                     (__attribute__((address_space(3))) void*)(l), 16, 0, 0)

// ---------------- convert fp32 -> bf16 ----------------
__global__ __launch_bounds__(256) void k_convert_bf16(const float* __restrict__ in,
                                                      __hip_bfloat16* __restrict__ out, int n4) {
    int i = blockIdx.x * blockDim.x + threadIdx.x;
    if (i >= n4) return;
    float4 v = ((const float4*)in)[i];
    union { __hip_bfloat16 b[4]; ushort4 u; } cv;
    cv.b[0] = __float2bfloat16(v.x);
    cv.b[1] = __float2bfloat16(v.y);
    cv.b[2] = __float2bfloat16(v.z);
    cv.b[3] = __float2bfloat16(v.w);
    *(ushort4*)(out + 4l * i) = cv.u;
}

// ---------------- 512x512 transpose + convert to bf16 ----------------
__global__ __launch_bounds__(1024) void k_transpose_bf16(const float* __restrict__ in,
                                                         __hip_bfloat16* __restrict__ out) {
    __shared__ float tile[32][33];
    int bx = blockIdx.x * 32;
    int by = blockIdx.y * 32;
    int tx = threadIdx.x, ty = threadIdx.y;
    tile[ty][tx] = in[(by + ty) * 512 + bx + tx];
    __syncthreads();
    out[(bx + ty) * 512 + by + tx] = __float2bfloat16(tile[tx][ty]);
}

// ---------------- MEGA GEMM: 128x128 tile, BK=64 (m97 structure + swizzle) ----
// 157x20=3140 blocks; 32 MFMA/wave per barrier-phase (2x R8) to amortize the
// vmcnt(0)+s_barrier drain that R8 showed is the limiter (FETCH already
// compulsory 26MB, MfmaUtil 13%). XCD swizzle keeps A-panel L2-local.
__global__ __launch_bounds__(256)
void k_gemm128(const __hip_bfloat16* __restrict__ A, const __hip_bfloat16* __restrict__ Bt,
               __hip_bfloat16* __restrict__ Cb, int c_ld, int M, int CT) {
    const int RT = (M + 127) >> 7;
    const int xcd = blockIdx.x & 7;
    const int k_ = blockIdx.x >> 3;
    const int ctile = k_ % CT;
    const int rtile = (k_ / CT) * 8 + xcd;
    if (rtile >= RT) return;

    __shared__ __hip_bfloat16 As[128 * 64];  // 16 KB; 16B-block b = [q=b>>7][r=b&127]
    __shared__ __hip_bfloat16 Bs[128 * 64];  // 16 KB
    const int tid = threadIdx.x;
    const int lane = tid & 63;
    const int wave = tid >> 6;
    const int row0 = rtile * 128;
    const int col0 = ctile * 128;
    const int wm = (wave >> 1) * 64;
    const int wn = (wave & 1) * 64;
    const int q8 = lane >> 4;
    const int l15 = lane & 15;

    int ar_ = row0 + (tid & 127);
    if (ar_ >= M) ar_ = M - 1;
    const __hip_bfloat16* aptr = A + (size_t)ar_ * DD + (tid >> 7) * 8;
    const __hip_bfloat16* bptr = Bt + (size_t)(col0 + (tid & 127)) * DD + (tid >> 7) * 8;
    __hip_bfloat16* alds = As + (size_t)tid * 8;
    __hip_bfloat16* blds = Bs + (size_t)tid * 8;

    floatx4 acc[4][4];
#pragma unroll
    for (int a = 0; a < 4; a++)
#pragma unroll
        for (int b = 0; b < 4; b++) acc[a][b] = (floatx4){0.f, 0.f, 0.f, 0.f};

    for (int k0 = 0; k0 < DD; k0 += 64) {
        __syncthreads();
#pragma unroll
        for (int j = 0; j < 4; j++) {  // q advances by 2 per instr (+16 elems)
            GLOAD_LDS16(aptr + k0 + j * 16, alds + (size_t)j * 256 * 8);
            GLOAD_LDS16(bptr + k0 + j * 16, blds + (size_t)j * 256 * 8);
        }
        __syncthreads();
#pragma unroll
        for (int kk = 0; kk < 2; kk++) {
            short8 af[4], bf[4];
#pragma unroll
            for (int mi = 0; mi < 4; mi++)
                af[mi] =
                    *(const short8*)(As + ((size_t)(kk * 4 + q8) * 128 + wm + mi * 16 + l15) * 8);
#pragma unroll
            for (int ni = 0; ni < 4; ni++)
                bf[ni] =
                    *(const short8*)(Bs + ((size_t)(kk * 4 + q8) * 128 + wn + ni * 16 + l15) * 8);
#pragma unroll
            for (int mi = 0; mi < 4; mi++)
#pragma unroll
                for (int ni = 0; ni < 4; ni++)
                    acc[mi][ni] = __builtin_amdgcn_mfma_f32_16x16x32_bf16(af[mi], bf[ni],
                                                                          acc[mi][ni], 0, 0, 0);
        }
    }

#pragma unroll
    for (int mi = 0; mi < 4; mi++)
#pragma unroll
        for (int ni = 0; ni < 4; ni++)
#pragma unroll
            for (int r = 0; r < 4; r++) {
                int grow = row0 + wm + mi * 16 + q8 * 4 + r;
                int gcol = col0 + wn + ni * 16 + l15;
                if (grow < M) Cb[(size_t)grow * c_ld + gcol] = __float2bfloat16(acc[mi][ni][r]);
            }
}

// ---------------- chain GEMM: 64x128 tile, BK=64, swizzle (R8-proven) ----------
// mode 1: Cf = relu(C + bf16 addend) fp32. mode 2: Cb = bf16(relu(C + addend)).
__global__ __launch_bounds__(256)
void k_gemm(const __hip_bfloat16* __restrict__ A, const __hip_bfloat16* __restrict__ Bt,
            float* __restrict__ Cf, __hip_bfloat16* __restrict__ Cb,
            const __hip_bfloat16* __restrict__ addend, int add_ld, int add_off, int c_ld,
            int M, int CT, int mode) {
    const int RT = (M + 63) >> 6;
    const int xcd = blockIdx.x & 7;
    const int k_ = blockIdx.x >> 3;
    const int ctile = k_ % CT;
    const int rtile = (k_ / CT) * 8 + xcd;
    if (rtile >= RT) return;

    __shared__ __hip_bfloat16 As[64 * 64];
    __shared__ __hip_bfloat16 Bs[128 * 64];
    const int tid = threadIdx.x;
    const int lane = tid & 63;
    const int wave = tid >> 6;
    const int row0 = rtile * 64;
    const int col0 = ctile * 128;
    const int wm = (wave >> 1) * 32;
    const int wn = (wave & 1) * 64;
    const int q8 = lane >> 4;
    const int l15 = lane & 15;

    int ar_ = row0 + (tid & 63);
    if (ar_ >= M) ar_ = M - 1;
    const __hip_bfloat16* aptr = A + (size_t)ar_ * DD + (tid >> 6) * 8;
    __hip_bfloat16* alds = As + (size_t)tid * 8;
    const __hip_bfloat16* bptr = Bt + (size_t)(col0 + (tid & 127)) * DD + (tid >> 7) * 8;
    __hip_bfloat16* blds = Bs + (size_t)tid * 8;

    floatx4 acc[2][4];
#pragma unroll
    for (int a = 0; a < 2; a++)
#pragma unroll
        for (int b = 0; b < 4; b++) acc[a][b] = (floatx4){0.f, 0.f, 0.f, 0.f};

    for (int k0 = 0; k0 < DD; k0 += 64) {
        __syncthreads();
        GLOAD_LDS16(aptr + k0, alds);
        GLOAD_LDS16(aptr + k0 + 32, alds + 256 * 8);
#pragma unroll
        for (int j = 0; j < 4; j++)
            GLOAD_LDS16(bptr + k0 + j * 16, blds + (size_t)j * 256 * 8);
        __syncthreads();
#pragma unroll
        for (int kk = 0; kk < 2; kk++) {
            short8 af[2], bf[4];
#pragma unroll
            for (int mi = 0; mi < 2; mi++)
                af[mi] =
                    *(const short8*)(As + ((size_t)(kk * 4 + q8) * 64 + wm + mi * 16 + l15) * 8);
#pragma unroll
            for (int ni = 0; ni < 4; ni++)
                bf[ni] =
                    *(const short8*)(Bs + ((size_t)(kk * 4 + q8) * 128 + wn + ni * 16 + l15) * 8);
#pragma unroll
            for (int mi = 0; mi < 2; mi++)
#pragma unroll
                for (int ni = 0; ni < 4; ni++)
                    acc[mi][ni] = __builtin_amdgcn_mfma_f32_16x16x32_bf16(af[mi], bf[ni],
                                                                          acc[mi][ni], 0, 0, 0);
        }
    }

#pragma unroll
    for (int mi = 0; mi < 2; mi++)
#pragma unroll
        for (int ni = 0; ni < 4; ni++)
#pragma unroll
            for (int r = 0; r < 4; r++) {
                int grow = row0 + wm + mi * 16 + q8 * 4 + r;
                int gcol = col0 + wn + ni * 16 + l15;
                if (grow < M) {
                    float v = acc[mi][ni][r];
                    v += bfbits2f(*(const unsigned short*)(addend + (size_t)grow * add_ld +
                                                           add_off + gcol));
                    v = v > 0.f ? v : 0.f;
                    if (mode == 1) Cf[(size_t)grow * c_ld + gcol] = v;
                    else Cb[(size_t)grow * c_ld + gcol] = __float2bfloat16(v);
                }
            }
}

// ---------------- el/er for all 4 relations in one pass over h_all ----------------
__global__ __launch_bounds__(256)
void k_el_er4(const __hip_bfloat16* __restrict__ h_all, const float* __restrict__ al0,
              const float* __restrict__ al1, const float* __restrict__ al2,
              const float* __restrict__ al3, const float* __restrict__ ar0,
              const float* __restrict__ ar1, const float* __restrict__ ar2,
              const float* __restrict__ ar3, float* __restrict__ el4, float* __restrict__ er4) {
    int row = blockIdx.x;
    int rel = threadIdx.x >> 6, lane = threadIdx.x & 63;
    const float* alp = rel == 0 ? al0 : rel == 1 ? al1 : rel == 2 ? al2 : al3;
    const float* arp = rel == 0 ? ar0 : rel == 1 ? ar1 : rel == 2 ? ar2 : ar3;
    uint4 hv = *(const uint4*)(h_all + (size_t)row * NH + rel * 512 + lane * 8);
    const unsigned short* hs = (const unsigned short*)&hv;
    float4 a0 = *(const float4*)(alp + lane * 8);
    float4 a1 = *(const float4*)(alp + lane * 8 + 4);
    float4 r0 = *(const float4*)(arp + lane * 8);
    float4 r1 = *(const float4*)(arp + lane * 8 + 4);
    float hf[8];
#pragma unroll
    for (int j = 0; j < 8; j++) hf[j] = bfbits2f(hs[j]);
    float sl = hf[0] * a0.x + hf[1] * a0.y + hf[2] * a0.z + hf[3] * a0.w +
               hf[4] * a1.x + hf[5] * a1.y + hf[6] * a1.z + hf[7] * a1.w;
    float sr = hf[0] * r0.x + hf[1] * r0.y + hf[2] * r0.z + hf[3] * r0.w +
               hf[4] * r1.x + hf[5] * r1.y + hf[6] * r1.z + hf[7] * r1.w;
#pragma unroll
    for (int off = 32; off > 0; off >>= 1) {
        sl += __shfl_down(sl, off);
        sr += __shfl_down(sr, off);
    }
    if (lane == 0) {
        el4[rel * NN + row] = sl;
        er4[rel * NN + row] = sr;
    }
}

// ---------------- CSR build (batched over 4 relations) ----------------
__global__ void k_zero_i32(int* p, int n) {
    int i = blockIdx.x * blockDim.x + threadIdx.x;
    if (i < n) p[i] = 0;
}

__global__ void k_count4(const int* __restrict__ e0, const int* __restrict__ e1,
                         const int* __restrict__ e2, const int* __restrict__ e3,
                         int* __restrict__ deg4) {
    int g = blockIdx.x * blockDim.x + threadIdx.x;
    if (g >= 4 * EE) return;
    int rel = g / EE;
    int e = g - rel * EE;
    const int* ed = rel == 0 ? e0 : rel == 1 ? e1 : rel == 2 ? e2 : e3;
    atomicAdd(&deg4[rel * NN + ed[EE + e]], 1);
}

__global__ __launch_bounds__(1024)
void k_scan4(const int* __restrict__ deg4, int* __restrict__ rp4, int* __restrict__ cur4) {
    const int rel = blockIdx.x;
    const int* deg = deg4 + rel * NN;
    int* row_ptr = rp4 + rel * (NN + 1);
    int* cursor = cur4 + rel * NN;
    __shared__ int sm[1024];
    int t = threadIdx.x;
    const int CH = 20;
    int begin = t * CH;
    int end = begin + CH;
    if (end > NN) end = NN;
    int s = 0;
    if (begin < NN)
        for (int i = begin; i < end; i++) s += deg[i];
    sm[t] = s;
    __syncthreads();
    for (int off = 1; off < 1024; off <<= 1) {
        int v = (t >= off) ? sm[t - off] : 0;
        __syncthreads();
        sm[t] += v;
        __syncthreads();
    }
    int run = sm[t] - s;
    if (begin < NN) {
        for (int i = begin; i < end; i++) {
            row_ptr[i] = run;
            cursor[i] = run;
            run += deg[i];
        }
        if (end == NN) row_ptr[NN] = run;
    }
}

__global__ void k_scatter4(const int* __restrict__ e0, const int* __restrict__ e1,
                           const int* __restrict__ e2, const int* __restrict__ e3,
                           int* __restrict__ cur4, int* __restrict__ csr4) {
    int g = blockIdx.x * blockDim.x + threadIdx.x;
    if (g >= 4 * EE) return;
    int rel = g / EE;
    int e = g - rel * EE;
    const int* ed = rel == 0 ? e0 : rel == 1 ? e1 : rel == 2 ? e2 : e3;
    int dst = ed[EE + e];
    int pos = atomicAdd(&cur4[rel * NN + dst], 1);
    csr4[rel * EE + pos] = ed[e];
}

// ---------------- BATCHED edge-softmax + aggregate: all 4 relations ----------------
// blockIdx.y = relation. gat4[rel][dst][:] = sum_j alpha_j h_rel[src_j][:].
// 80000 waves (4x the per-rel version) -> 4x latency hiding for the gathers.
__global__ __launch_bounds__(256)
void k_agg4(const int* __restrict__ rp4, const int* __restrict__ csr4,
            const float* __restrict__ el4, const float* __restrict__ er4,
            const __hip_bfloat16* __restrict__ h_all, __hip_bfloat16* __restrict__ gat4,
            float* __restrict__ alpha4) {
    const int rel = blockIdx.y;
    const int* row_ptr = rp4 + rel * (NN + 1);
    const int* csr_src = csr4 + (size_t)rel * EE;
    const float* el = el4 + rel * NN;
    const float* er = er4 + rel * NN;
    const __hip_bfloat16* h = h_all + (size_t)rel * 512;
    float* alpha_tmp = alpha4 + (size_t)rel * EE;

    int d = (blockIdx.x * blockDim.x + threadIdx.x) >> 6;
    int lane = threadIdx.x & 63;
    if (d >= NN) return;
    int s0 = row_ptr[d], s1 = row_ptr[d + 1];
    int deg = s1 - s0;
    int base = lane * 8;
    float acc[8] = {0.f, 0.f, 0.f, 0.f, 0.f, 0.f, 0.f, 0.f};

    if (deg <= 64) {
        int sv = 0;
        float av = 0.f;
        if (lane < deg) sv = csr_src[s0 + lane];
        float erd = er[d];
        float v = -1e30f;
        if (lane < deg) {
            float e = el[sv] + erd;
            v = e >= 0.f ? e : 0.2f * e;
        }
        float m = v;
#pragma unroll
        for (int off = 32; off > 0; off >>= 1) m = fmaxf(m, __shfl_xor(m, off));
        float wgt = (lane < deg) ? __expf(v - m) : 0.f;
        float s = wgt;
#pragma unroll
        for (int off = 32; off > 0; off >>= 1) s += __shfl_xor(s, off);
        av = wgt / s;
        int t = 0;
        for (; t + 1 < deg; t += 2) {
            int sA = __shfl(sv, t), sB = __shfl(sv, t + 1);
            float aA = __shfl(av, t), aB = __shfl(av, t + 1);
            uint4 hv0 = *(const uint4*)(h + (size_t)sA * NH + base);
            uint4 hv1 = *(const uint4*)(h + (size_t)sB * NH + base);
            const unsigned short* h0 = (const unsigned short*)&hv0;
            const unsigned short* h1 = (const unsigned short*)&hv1;
#pragma unroll
            for (int k = 0; k < 8; k++) acc[k] += aA * bfbits2f(h0[k]) + aB * bfbits2f(h1[k]);
        }
        if (t < deg) {
            int sA = __shfl(sv, t);
            float aA = __shfl(av, t);
            uint4 hv0 = *(const uint4*)(h + (size_t)sA * NH + base);
            const unsigned short* h0 = (const unsigned short*)&hv0;
#pragma unroll
            for (int k = 0; k < 8; k++) acc[k] += aA * bfbits2f(h0[k]);
        }
    } else {
        float erd = er[d];
        float m = -1e30f;
        for (int j = s0 + lane; j < s1; j += 64) {
            float e = el[csr_src[j]] + erd;
            e = e >= 0.f ? e : 0.2f * e;
            alpha_tmp[j] = e;
            m = fmaxf(m, e);
        }
#pragma unroll
        for (int off = 32; off > 0; off >>= 1) m = fmaxf(m, __shfl_xor(m, off));
        float s = 0.f;
        for (int j = s0 + lane; j < s1; j += 64) {
            float wv = __expf(alpha_tmp[j] - m);
            alpha_tmp[j] = wv;
            s += wv;
        }
#pragma unroll
        for (int off = 32; off > 0; off >>= 1) s += __shfl_xor(s, off);
        float inv = 1.f / s;
        for (int j0 = 0; j0 < deg; j0 += 64) {
            int cnt = deg - j0;
            if (cnt > 64) cnt = 64;
            int sv = 0;
            float av = 0.f;
            if (lane < cnt) {
                sv = csr_src[s0 + j0 + lane];
                av = alpha_tmp[s0 + j0 + lane] * inv;
            }
            for (int t = 0; t < cnt; t++) {
                int sA = __shfl(sv, t);
                float aA = __shfl(av, t);
                uint4 hv0 = *(const uint4*)(h + (size_t)sA * NH + base);
                const unsigned short* h0 = (const unsigned short*)&hv0;
#pragma unroll
                for (int k = 0; k < 8; k++) acc[k] += aA * bfbits2f(h0[k]);
            }
        }
    }

    union { __hip_bfloat16 b[8]; uint4 u; } cv;
#pragma unroll
    for (int k = 0; k < 8; k++) cv.b[k] = __float2bfloat16(acc[k]);
    *(uint4*)(gat4 + (size_t)rel * NN * DD + (size_t)d * DD + base) = cv.u;
}

// ---------------- t = gat_i + (out_prev) + bias, bf16 out ----------------
__global__ __launch_bounds__(256)
void k_addt(const __hip_bfloat16* __restrict__ gat, const __hip_bfloat16* __restrict__ out_prev,
            const float* __restrict__ bias, __hip_bfloat16* __restrict__ t_out, int use_prev) {
    int i = blockIdx.x * blockDim.x + threadIdx.x;  // 8 elems per thread
    if (i >= NN * DD / 8) return;
    size_t idx = (size_t)i * 8;
    int c = (int)(idx & 511);
    uint4 gv = *(const uint4*)(gat + idx);
    const unsigned short* gp = (const unsigned short*)&gv;
    float4 b0 = *(const float4*)(bias + c);
    float4 b1 = *(const float4*)(bias + c + 4);
    float acc[8];
#pragma unroll
    for (int k = 0; k < 8; k++) acc[k] = bfbits2f(gp[k]);
    acc[0] += b0.x; acc[1] += b0.y; acc[2] += b0.z; acc[3] += b0.w;
    acc[4] += b1.x; acc[5] += b1.y; acc[6] += b1.z; acc[7] += b1.w;
    if (use_prev) {
        uint4 pv = *(const uint4*)(out_prev + idx);
        const unsigned short* pp = (const unsigned short*)&pv;
#pragma unroll
        for (int k = 0; k < 8; k++) acc[k] += bfbits2f(pp[k]);
    }
    union { __hip_bfloat16 b[8]; uint4 u; } cv;
#pragma unroll
    for (int k = 0; k < 8; k++) cv.b[k] = __float2bfloat16(acc[k]);
    *(uint4*)(t_out + idx) = cv.u;
}

extern "C" void kernel_launch(void* const* d_in, const int* in_sizes, int n_in,
                              void* d_out, int out_size, void* d_ws, size_t ws_size,
                              hipStream_t stream) {
    const float* x = (const float*)d_in[0];
    const int* edges[4] = {(const int*)d_in[1], (const int*)d_in[5], (const int*)d_in[9],
                           (const int*)d_in[13]};
    const float* W[4] = {(const float*)d_in[2], (const float*)d_in[6], (const float*)d_in[10],
                         (const float*)d_in[14]};
    const float* al[4] = {(const float*)d_in[3], (const float*)d_in[7], (const float*)d_in[11],
                          (const float*)d_in[15]};
    const float* ar[4] = {(const float*)d_in[4], (const float*)d_in[8], (const float*)d_in[12],
                          (const float*)d_in[16]};
    const float* Wl = (const float*)d_in[17];
    const float* bias = (const float*)d_in[18];
    float* out = (float*)d_out;

    char* w = (char*)d_ws;
    auto alloc = [&](size_t bytes) {
        char* p = w;
        w += (bytes + 255) & ~(size_t)255;
        return p;
    };
    __hip_bfloat16* x_bf = (__hip_bfloat16*)alloc((size_t)NN * DD * 2);
    __hip_bfloat16* h_all = (__hip_bfloat16*)alloc((size_t)NN * NH * 2);   // [h0..h3|xwl]
    __hip_bfloat16* gat4 = (__hip_bfloat16*)alloc((size_t)4 * NN * DD * 2);
    __hip_bfloat16* t_bf = (__hip_bfloat16*)alloc((size_t)NN * DD * 2);
    __hip_bfloat16* out_bf = (__hip_bfloat16*)alloc((size_t)NN * DD * 2);
    __hip_bfloat16* Bt_all = (__hip_bfloat16*)alloc((size_t)NH * DD * 2);  // [W0..W3,WlTop]^T
    __hip_bfloat16* WlTb = (__hip_bfloat16*)alloc((size_t)DD * DD * 2);
    float* el4 = (float*)alloc((size_t)4 * NN * 4);
    float* er4 = (float*)alloc((size_t)4 * NN * 4);
    int* deg4 = (int*)alloc((size_t)4 * NN * 4);
    int* rp4 = (int*)alloc((size_t)4 * (NN + 1) * 4);
    int* cur4 = (int*)alloc((size_t)4 * NN * 4);
    int* csr4 = (int*)alloc((size_t)4 * EE * 4);
    float* alpha4 = (float*)alloc((size_t)4 * EE * 4);

    // preprocessing
    k_convert_bf16<<<(NN * DD / 4 + 255) / 256, 256, 0, stream>>>(x, x_bf, NN * DD / 4);
    dim3 tb(32, 32), tg(16, 16);
    for (int i = 0; i < 4; i++)
        k_transpose_bf16<<<tg, tb, 0, stream>>>(W[i], Bt_all + (size_t)i * DD * DD);
    k_transpose_bf16<<<tg, tb, 0, stream>>>(Wl, Bt_all + (size_t)4 * DD * DD);
    k_transpose_bf16<<<tg, tb, 0, stream>>>(Wl + DD * DD, WlTb);

    // CSR for all 4 relations
    k_zero_i32<<<(4 * NN + 255) / 256, 256, 0, stream>>>(deg4, 4 * NN);
    k_count4<<<(4 * EE + 255) / 256, 256, 0, stream>>>(edges[0], edges[1], edges[2], edges[3], deg4);
    k_scan4<<<4, 1024, 0, stream>>>(deg4, rp4, cur4);
    k_scatter4<<<(4 * EE + 255) / 256, 256, 0, stream>>>(edges[0], edges[1], edges[2], edges[3],
                                                         cur4, csr4);

    // MEGA-GEMM: h_all = x @ [W0|W1|W2|W3|Wl_top], 128x128 tiles, CT=20
    const int RT128 = (NN + 127) / 128;          // 157
    const int RT128p8 = ((RT128 + 7) / 8) * 8;   // 160
    k_gemm128<<<RT128p8 * 20, 256, 0, stream>>>(x_bf, Bt_all, h_all, NH, NN, 20);

    // el/er all 4 relations
    k_el_er4<<<NN, 256, 0, stream>>>(h_all, al[0], al[1], al[2], al[3], ar[0], ar[1], ar[2], ar[3],
                                     el4, er4);

    // batched aggregate: gat4[rel] for all relations in one launch
    dim3 gagg((NN * 64 + 255) / 256, 4);
    k_agg4<<<gagg, 256, 0, stream>>>(rp4, csr4, el4, er4, h_all, gat4, alpha4);

    const int RT64 = (NN + 63) / 64;           // 313
    const int RT64p8 = ((RT64 + 7) / 8) * 8;   // 320
    const int NADD = (NN * DD / 8 + 255) / 256;
    for (int i = 0; i < 4; i++) {
        k_addt<<<NADD, 256, 0, stream>>>(gat4 + (size_t)i * NN * DD, out_bf, bias, t_bf,
                                         i > 0 ? 1 : 0);
        // out = relu(xwl + t @ Wl_bot); xwl at h_all cols [2048,2560). CT=4.
        if (i < 3)
            k_gemm<<<RT64p8 * 4, 256, 0, stream>>>(t_bf, WlTb, nullptr, out_bf, h_all, NH, 2048,
                                                   DD, NN, 4, 2);
        else
            k_gemm<<<RT64p8 * 4, 256, 0, stream>>>(t_bf, WlTb, out, nullptr, h_all, NH, 2048, DD,
                                                   NN, 4, 1);
    }
}

// Round 10
// 667.408 us; speedup vs baseline: 1.4339x; 1.0104x over previous
//
#include <hip/hip_runtime.h>
#include <hip/hip_bf16.h>

#define NN 20000
#define DD 512
#define EE 150000
#define NH 2560  // stacked GEMM width: 4*512 (W_i) + 512 (Wl_top)

typedef __attribute__((ext_vector_type(8))) short short8;
typedef __attribute__((ext_vector_type(4))) float floatx4;

static __device__ __forceinline__ float bfbits2f(unsigned short u) {
    unsigned int x = ((unsigned int)u) << 16;
    return __uint_as_float(x);
}

#define GLOAD_LDS16(g, l)                                                        \
    __builtin_amdgcn_global_load_lds((const __attribute__((address_space(1))) void*)(g), \
                                     (__attribute__((address_space(3))) void*)(l), 16, 0, 0)

// ---------------- convert fp32 -> bf16 ----------------
__global__ __launch_bounds__(256) void k_convert_bf16(const float* __restrict__ in,
                                                      __hip_bfloat16* __restrict__ out, int n4) {
    int i = blockIdx.x * blockDim.x + threadIdx.x;
    if (i >= n4) return;
    float4 v = ((const float4*)in)[i];
    union { __hip_bfloat16 b[4]; ushort4 u; } cv;
    cv.b[0] = __float2bfloat16(v.x);
    cv.b[1] = __float2bfloat16(v.y);
    cv.b[2] = __float2bfloat16(v.z);
    cv.b[3] = __float2bfloat16(v.w);
    *(ushort4*)(out + 4l * i) = cv.u;
}

// ---------------- 512x512 transpose + convert to bf16 ----------------
__global__ __launch_bounds__(1024) void k_transpose_bf16(const float* __restrict__ in,
                                                         __hip_bfloat16* __restrict__ out) {
    __shared__ float tile[32][33];
    int bx = blockIdx.x * 32;
    int by = blockIdx.y * 32;
    int tx = threadIdx.x, ty = threadIdx.y;
    tile[ty][tx] = in[(by + ty) * 512 + bx + tx];
    __syncthreads();
    out[(bx + ty) * 512 + by + tx] = __float2bfloat16(tile[tx][ty]);
}

// ---------------- MEGA GEMM: 128x128 tile, BK=64, XCD swizzle (R9 best) ----
__global__ __launch_bounds__(256)
void k_gemm128(const __hip_bfloat16* __restrict__ A, const __hip_bfloat16* __restrict__ Bt,
               __hip_bfloat16* __restrict__ Cb, int c_ld, int M, int CT) {
    const int RT = (M + 127) >> 7;
    const int xcd = blockIdx.x & 7;
    const int k_ = blockIdx.x >> 3;
    const int ctile = k_ % CT;
    const int rtile = (k_ / CT) * 8 + xcd;
    if (rtile >= RT) return;

    __shared__ __hip_bfloat16 As[128 * 64];
    __shared__ __hip_bfloat16 Bs[128 * 64];
    const int tid = threadIdx.x;
    const int lane = tid & 63;
    const int wave = tid >> 6;
    const int row0 = rtile * 128;
    const int col0 = ctile * 128;
    const int wm = (wave >> 1) * 64;
    const int wn = (wave & 1) * 64;
    const int q8 = lane >> 4;
    const int l15 = lane & 15;

    int ar_ = row0 + (tid & 127);
    if (ar_ >= M) ar_ = M - 1;
    const __hip_bfloat16* aptr = A + (size_t)ar_ * DD + (tid >> 7) * 8;
    const __hip_bfloat16* bptr = Bt + (size_t)(col0 + (tid & 127)) * DD + (tid >> 7) * 8;
    __hip_bfloat16* alds = As + (size_t)tid * 8;
    __hip_bfloat16* blds = Bs + (size_t)tid * 8;

    floatx4 acc[4][4];
#pragma unroll
    for (int a = 0; a < 4; a++)
#pragma unroll
        for (int b = 0; b < 4; b++) acc[a][b] = (floatx4){0.f, 0.f, 0.f, 0.f};

    for (int k0 = 0; k0 < DD; k0 += 64) {
        __syncthreads();
#pragma unroll
        for (int j = 0; j < 4; j++) {
            GLOAD_LDS16(aptr + k0 + j * 16, alds + (size_t)j * 256 * 8);
            GLOAD_LDS16(bptr + k0 + j * 16, blds + (size_t)j * 256 * 8);
        }
        __syncthreads();
#pragma unroll
        for (int kk = 0; kk < 2; kk++) {
            short8 af[4], bf[4];
#pragma unroll
            for (int mi = 0; mi < 4; mi++)
                af[mi] =
                    *(const short8*)(As + ((size_t)(kk * 4 + q8) * 128 + wm + mi * 16 + l15) * 8);
#pragma unroll
            for (int ni = 0; ni < 4; ni++)
                bf[ni] =
                    *(const short8*)(Bs + ((size_t)(kk * 4 + q8) * 128 + wn + ni * 16 + l15) * 8);
#pragma unroll
            for (int mi = 0; mi < 4; mi++)
#pragma unroll
                for (int ni = 0; ni < 4; ni++)
                    acc[mi][ni] = __builtin_amdgcn_mfma_f32_16x16x32_bf16(af[mi], bf[ni],
                                                                          acc[mi][ni], 0, 0, 0);
        }
    }

#pragma unroll
    for (int mi = 0; mi < 4; mi++)
#pragma unroll
        for (int ni = 0; ni < 4; ni++)
#pragma unroll
            for (int r = 0; r < 4; r++) {
                int grow = row0 + wm + mi * 16 + q8 * 4 + r;
                int gcol = col0 + wn + ni * 16 + l15;
                if (grow < M) Cb[(size_t)grow * c_ld + gcol] = __float2bfloat16(acc[mi][ni][r]);
            }
}

// ---------------- CHAIN GEMM with fused t-propagation ----------------
// C = t_i @ Wl_bot; v = relu(C + xwl).  i<3: t_next = bf16(v + gnext)
// (gnext = gat_{i+1}+bias from agg4) -- out_i never materialized.
// i=3: outf = v (fp32).  64x128 tile, BK=64, XCD swizzle, CT=4.
__global__ __launch_bounds__(256)
void k_chain(const __hip_bfloat16* __restrict__ A, const __hip_bfloat16* __restrict__ Bt,
             const __hip_bfloat16* __restrict__ xwl, const __hip_bfloat16* __restrict__ gnext,
             __hip_bfloat16* __restrict__ t_next, float* __restrict__ outf, int M) {
    const int CT = 4;
    const int RT = (M + 63) >> 6;
    const int xcd = blockIdx.x & 7;
    const int k_ = blockIdx.x >> 3;
    const int ctile = k_ % CT;
    const int rtile = (k_ / CT) * 8 + xcd;
    if (rtile >= RT) return;

    __shared__ __hip_bfloat16 As[64 * 64];
    __shared__ __hip_bfloat16 Bs[128 * 64];
    const int tid = threadIdx.x;
    const int lane = tid & 63;
    const int wave = tid >> 6;
    const int row0 = rtile * 64;
    const int col0 = ctile * 128;
    const int wm = (wave >> 1) * 32;
    const int wn = (wave & 1) * 64;
    const int q8 = lane >> 4;
    const int l15 = lane & 15;

    int ar_ = row0 + (tid & 63);
    if (ar_ >= M) ar_ = M - 1;
    const __hip_bfloat16* aptr = A + (size_t)ar_ * DD + (tid >> 6) * 8;
    __hip_bfloat16* alds = As + (size_t)tid * 8;
    const __hip_bfloat16* bptr = Bt + (size_t)(col0 + (tid & 127)) * DD + (tid >> 7) * 8;
    __hip_bfloat16* blds = Bs + (size_t)tid * 8;

    floatx4 acc[2][4];
#pragma unroll
    for (int a = 0; a < 2; a++)
#pragma unroll
        for (int b = 0; b < 4; b++) acc[a][b] = (floatx4){0.f, 0.f, 0.f, 0.f};

    for (int k0 = 0; k0 < DD; k0 += 64) {
        __syncthreads();
        GLOAD_LDS16(aptr + k0, alds);
        GLOAD_LDS16(aptr + k0 + 32, alds + 256 * 8);
#pragma unroll
        for (int j = 0; j < 4; j++)
            GLOAD_LDS16(bptr + k0 + j * 16, blds + (size_t)j * 256 * 8);
        __syncthreads();
#pragma unroll
        for (int kk = 0; kk < 2; kk++) {
            short8 af[2], bf[4];
#pragma unroll
            for (int mi = 0; mi < 2; mi++)
                af[mi] =
                    *(const short8*)(As + ((size_t)(kk * 4 + q8) * 64 + wm + mi * 16 + l15) * 8);
#pragma unroll
            for (int ni = 0; ni < 4; ni++)
                bf[ni] =
                    *(const short8*)(Bs + ((size_t)(kk * 4 + q8) * 128 + wn + ni * 16 + l15) * 8);
#pragma unroll
            for (int mi = 0; mi < 2; mi++)
#pragma unroll
                for (int ni = 0; ni < 4; ni++)
                    acc[mi][ni] = __builtin_amdgcn_mfma_f32_16x16x32_bf16(af[mi], bf[ni],
                                                                          acc[mi][ni], 0, 0, 0);
        }
    }

#pragma unroll
    for (int mi = 0; mi < 2; mi++)
#pragma unroll
        for (int ni = 0; ni < 4; ni++)
#pragma unroll
            for (int r = 0; r < 4; r++) {
                int grow = row0 + wm + mi * 16 + q8 * 4 + r;
                int gcol = col0 + wn + ni * 16 + l15;
                if (grow < M) {
                    float v = acc[mi][ni][r];
                    v += bfbits2f(*(const unsigned short*)(xwl + (size_t)grow * NH + 2048 + gcol));
                    v = v > 0.f ? v : 0.f;  // v = out_i
                    size_t idx = (size_t)grow * DD + gcol;
                    if (t_next) {
                        v += bfbits2f(*(const unsigned short*)(gnext + idx));
                        t_next[idx] = __float2bfloat16(v);
                    } else {
                        outf[idx] = v;
                    }
                }
            }
}

// ---------------- el/er for all 4 relations in one pass over h_all ----------------
__global__ __launch_bounds__(256)
void k_el_er4(const __hip_bfloat16* __restrict__ h_all, const float* __restrict__ al0,
              const float* __restrict__ al1, const float* __restrict__ al2,
              const float* __restrict__ al3, const float* __restrict__ ar0,
              const float* __restrict__ ar1, const float* __restrict__ ar2,
              const float* __restrict__ ar3, float* __restrict__ el4, float* __restrict__ er4) {
    int row = blockIdx.x;
    int rel = threadIdx.x >> 6, lane = threadIdx.x & 63;
    const float* alp = rel == 0 ? al0 : rel == 1 ? al1 : rel == 2 ? al2 : al3;
    const float* arp = rel == 0 ? ar0 : rel == 1 ? ar1 : rel == 2 ? ar2 : ar3;
    uint4 hv = *(const uint4*)(h_all + (size_t)row * NH + rel * 512 + lane * 8);
    const unsigned short* hs = (const unsigned short*)&hv;
    float4 a0 = *(const float4*)(alp + lane * 8);
    float4 a1 = *(const float4*)(alp + lane * 8 + 4);
    float4 r0 = *(const float4*)(arp + lane * 8);
    float4 r1 = *(const float4*)(arp + lane * 8 + 4);
    float hf[8];
#pragma unroll
    for (int j = 0; j < 8; j++) hf[j] = bfbits2f(hs[j]);
    float sl = hf[0] * a0.x + hf[1] * a0.y + hf[2] * a0.z + hf[3] * a0.w +
               hf[4] * a1.x + hf[5] * a1.y + hf[6] * a1.z + hf[7] * a1.w;
    float sr = hf[0] * r0.x + hf[1] * r0.y + hf[2] * r0.z + hf[3] * r0.w +
               hf[4] * r1.x + hf[5] * r1.y + hf[6] * r1.z + hf[7] * r1.w;
#pragma unroll
    for (int off = 32; off > 0; off >>= 1) {
        sl += __shfl_down(sl, off);
        sr += __shfl_down(sr, off);
    }
    if (lane == 0) {
        el4[rel * NN + row] = sl;
        er4[rel * NN + row] = sr;
    }
}

// ---------------- CSR build (batched over 4 relations) ----------------
__global__ void k_zero_i32(int* p, int n) {
    int i = blockIdx.x * blockDim.x + threadIdx.x;
    if (i < n) p[i] = 0;
}

__global__ void k_count4(const int* __restrict__ e0, const int* __restrict__ e1,
                         const int* __restrict__ e2, const int* __restrict__ e3,
                         int* __restrict__ deg4) {
    int g = blockIdx.x * blockDim.x + threadIdx.x;
    if (g >= 4 * EE) return;
    int rel = g / EE;
    int e = g - rel * EE;
    const int* ed = rel == 0 ? e0 : rel == 1 ? e1 : rel == 2 ? e2 : e3;
    atomicAdd(&deg4[rel * NN + ed[EE + e]], 1);
}

__global__ __launch_bounds__(1024)
void k_scan4(const int* __restrict__ deg4, int* __restrict__ rp4, int* __restrict__ cur4) {
    const int rel = blockIdx.x;
    const int* deg = deg4 + rel * NN;
    int* row_ptr = rp4 + rel * (NN + 1);
    int* cursor = cur4 + rel * NN;
    __shared__ int sm[1024];
    int t = threadIdx.x;
    const int CH = 20;
    int begin = t * CH;
    int end = begin + CH;
    if (end > NN) end = NN;
    int s = 0;
    if (begin < NN)
        for (int i = begin; i < end; i++) s += deg[i];
    sm[t] = s;
    __syncthreads();
    for (int off = 1; off < 1024; off <<= 1) {
        int v = (t >= off) ? sm[t - off] : 0;
        __syncthreads();
        sm[t] += v;
        __syncthreads();
    }
    int run = sm[t] - s;
    if (begin < NN) {
        for (int i = begin; i < end; i++) {
            row_ptr[i] = run;
            cursor[i] = run;
            run += deg[i];
        }
        if (end == NN) row_ptr[NN] = run;
    }
}

__global__ void k_scatter4(const int* __restrict__ e0, const int* __restrict__ e1,
                           const int* __restrict__ e2, const int* __restrict__ e3,
                           int* __restrict__ cur4, int* __restrict__ csr4) {
    int g = blockIdx.x * blockDim.x + threadIdx.x;
    if (g >= 4 * EE) return;
    int rel = g / EE;
    int e = g - rel * EE;
    const int* ed = rel == 0 ? e0 : rel == 1 ? e1 : rel == 2 ? e2 : e3;
    int dst = ed[EE + e];
    int pos = atomicAdd(&cur4[rel * NN + dst], 1);
    csr4[rel * EE + pos] = ed[e];
}

// ---------------- BATCHED edge-softmax + aggregate (+bias): all 4 relations ----
// gat4[rel][dst][:] = bias + sum_j alpha_j h_rel[src_j][:]   (g' = gat + bias)
__global__ __launch_bounds__(256)
void k_agg4(const int* __restrict__ rp4, const int* __restrict__ csr4,
            const float* __restrict__ el4, const float* __restrict__ er4,
            const __hip_bfloat16* __restrict__ h_all, const float* __restrict__ bias,
            __hip_bfloat16* __restrict__ gat4, float* __restrict__ alpha4) {
    const int rel = blockIdx.y;
    const int* row_ptr = rp4 + rel * (NN + 1);
    const int* csr_src = csr4 + (size_t)rel * EE;
    const float* el = el4 + rel * NN;
    const float* er = er4 + rel * NN;
    const __hip_bfloat16* h = h_all + (size_t)rel * 512;
    float* alpha_tmp = alpha4 + (size_t)rel * EE;

    int d = (blockIdx.x * blockDim.x + threadIdx.x) >> 6;
    int lane = threadIdx.x & 63;
    if (d >= NN) return;
    int s0 = row_ptr[d], s1 = row_ptr[d + 1];
    int deg = s1 - s0;
    int base = lane * 8;
    float acc[8] = {0.f, 0.f, 0.f, 0.f, 0.f, 0.f, 0.f, 0.f};

    if (deg <= 64) {
        int sv = 0;
        float av = 0.f;
        if (lane < deg) sv = csr_src[s0 + lane];
        float erd = er[d];
        float v = -1e30f;
        if (lane < deg) {
            float e = el[sv] + erd;
            v = e >= 0.f ? e : 0.2f * e;
        }
        float m = v;
#pragma unroll
        for (int off = 32; off > 0; off >>= 1) m = fmaxf(m, __shfl_xor(m, off));
        float wgt = (lane < deg) ? __expf(v - m) : 0.f;
        float s = wgt;
#pragma unroll
        for (int off = 32; off > 0; off >>= 1) s += __shfl_xor(s, off);
        av = wgt / s;
        int t = 0;
        for (; t + 3 < deg; t += 4) {
            int sA = __shfl(sv, t), sB = __shfl(sv, t + 1);
            int sC = __shfl(sv, t + 2), sD = __shfl(sv, t + 3);
            float aA = __shfl(av, t), aB = __shfl(av, t + 1);
            float aC = __shfl(av, t + 2), aD = __shfl(av, t + 3);
            uint4 hv0 = *(const uint4*)(h + (size_t)sA * NH + base);
            uint4 hv1 = *(const uint4*)(h + (size_t)sB * NH + base);
            uint4 hv2 = *(const uint4*)(h + (size_t)sC * NH + base);
            uint4 hv3 = *(const uint4*)(h + (size_t)sD * NH + base);
            const unsigned short* h0 = (const unsigned short*)&hv0;
            const unsigned short* h1 = (const unsigned short*)&hv1;
            const unsigned short* h2 = (const unsigned short*)&hv2;
            const unsigned short* h3 = (const unsigned short*)&hv3;
#pragma unroll
            for (int k = 0; k < 8; k++)
                acc[k] += aA * bfbits2f(h0[k]) + aB * bfbits2f(h1[k]) + aC * bfbits2f(h2[k]) +
                          aD * bfbits2f(h3[k]);
        }
        for (; t < deg; t++) {
            int sA = __shfl(sv, t);
            float aA = __shfl(av, t);
            uint4 hv0 = *(const uint4*)(h + (size_t)sA * NH + base);
            const unsigned short* h0 = (const unsigned short*)&hv0;
#pragma unroll
            for (int k = 0; k < 8; k++) acc[k] += aA * bfbits2f(h0[k]);
        }
    } else {
        float erd = er[d];
        float m = -1e30f;
        for (int j = s0 + lane; j < s1; j += 64) {
            float e = el[csr_src[j]] + erd;
            e = e >= 0.f ? e : 0.2f * e;
            alpha_tmp[j] = e;
            m = fmaxf(m, e);
        }
#pragma unroll
        for (int off = 32; off > 0; off >>= 1) m = fmaxf(m, __shfl_xor(m, off));
        float s = 0.f;
        for (int j = s0 + lane; j < s1; j += 64) {
            float wv = __expf(alpha_tmp[j] - m);
            alpha_tmp[j] = wv;
            s += wv;
        }
#pragma unroll
        for (int off = 32; off > 0; off >>= 1) s += __shfl_xor(s, off);
        float inv = 1.f / s;
        for (int j0 = 0; j0 < deg; j0 += 64) {
            int cnt = deg - j0;
            if (cnt > 64) cnt = 64;
            int sv = 0;
            float av = 0.f;
            if (lane < cnt) {
                sv = csr_src[s0 + j0 + lane];
                av = alpha_tmp[s0 + j0 + lane] * inv;
            }
            for (int t = 0; t < cnt; t++) {
                int sA = __shfl(sv, t);
                float aA = __shfl(av, t);
                uint4 hv0 = *(const uint4*)(h + (size_t)sA * NH + base);
                const unsigned short* h0 = (const unsigned short*)&hv0;
#pragma unroll
                for (int k = 0; k < 8; k++) acc[k] += aA * bfbits2f(h0[k]);
            }
        }
    }

    float4 b0 = *(const float4*)(bias + base);
    float4 b1 = *(const float4*)(bias + base + 4);
    acc[0] += b0.x; acc[1] += b0.y; acc[2] += b0.z; acc[3] += b0.w;
    acc[4] += b1.x; acc[5] += b1.y; acc[6] += b1.z; acc[7] += b1.w;
    union { __hip_bfloat16 b[8]; uint4 u; } cv;
#pragma unroll
    for (int k = 0; k < 8; k++) cv.b[k] = __float2bfloat16(acc[k]);
    *(uint4*)(gat4 + (size_t)rel * NN * DD + (size_t)d * DD + base) = cv.u;
}

extern "C" void kernel_launch(void* const* d_in, const int* in_sizes, int n_in,
                              void* d_out, int out_size, void* d_ws, size_t ws_size,
                              hipStream_t stream) {
    const float* x = (const float*)d_in[0];
    const int* edges[4] = {(const int*)d_in[1], (const int*)d_in[5], (const int*)d_in[9],
                           (const int*)d_in[13]};
    const float* W[4] = {(const float*)d_in[2], (const float*)d_in[6], (const float*)d_in[10],
                         (const float*)d_in[14]};
    const float* al[4] = {(const float*)d_in[3], (const float*)d_in[7], (const float*)d_in[11],
                          (const float*)d_in[15]};
    const float* ar[4] = {(const float*)d_in[4], (const float*)d_in[8], (const float*)d_in[12],
                          (const float*)d_in[16]};
    const float* Wl = (const float*)d_in[17];
    const float* bias = (const float*)d_in[18];
    float* out = (float*)d_out;

    char* w = (char*)d_ws;
    auto alloc = [&](size_t bytes) {
        char* p = w;
        w += (bytes + 255) & ~(size_t)255;
        return p;
    };
    __hip_bfloat16* x_bf = (__hip_bfloat16*)alloc((size_t)NN * DD * 2);
    __hip_bfloat16* h_all = (__hip_bfloat16*)alloc((size_t)NN * NH * 2);   // [h0..h3|xwl]
    __hip_bfloat16* gat4 = (__hip_bfloat16*)alloc((size_t)4 * NN * DD * 2);
    __hip_bfloat16* t_A = (__hip_bfloat16*)alloc((size_t)NN * DD * 2);
    __hip_bfloat16* t_B = (__hip_bfloat16*)alloc((size_t)NN * DD * 2);
    __hip_bfloat16* Bt_all = (__hip_bfloat16*)alloc((size_t)NH * DD * 2);  // [W0..W3,WlTop]^T
    __hip_bfloat16* WlTb = (__hip_bfloat16*)alloc((size_t)DD * DD * 2);
    float* el4 = (float*)alloc((size_t)4 * NN * 4);
    float* er4 = (float*)alloc((size_t)4 * NN * 4);
    int* deg4 = (int*)alloc((size_t)4 * NN * 4);
    int* rp4 = (int*)alloc((size_t)4 * (NN + 1) * 4);
    int* cur4 = (int*)alloc((size_t)4 * NN * 4);
    int* csr4 = (int*)alloc((size_t)4 * EE * 4);
    float* alpha4 = (float*)alloc((size_t)4 * EE * 4);

    // preprocessing
    k_convert_bf16<<<(NN * DD / 4 + 255) / 256, 256, 0, stream>>>(x, x_bf, NN * DD / 4);
    dim3 tb(32, 32), tg(16, 16);
    for (int i = 0; i < 4; i++)
        k_transpose_bf16<<<tg, tb, 0, stream>>>(W[i], Bt_all + (size_t)i * DD * DD);
    k_transpose_bf16<<<tg, tb, 0, stream>>>(Wl, Bt_all + (size_t)4 * DD * DD);
    k_transpose_bf16<<<tg, tb, 0, stream>>>(Wl + DD * DD, WlTb);

    // CSR for all 4 relations
    k_zero_i32<<<(4 * NN + 255) / 256, 256, 0, stream>>>(deg4, 4 * NN);
    k_count4<<<(4 * EE + 255) / 256, 256, 0, stream>>>(edges[0], edges[1], edges[2], edges[3], deg4);
    k_scan4<<<4, 1024, 0, stream>>>(deg4, rp4, cur4);
    k_scatter4<<<(4 * EE + 255) / 256, 256, 0, stream>>>(edges[0], edges[1], edges[2], edges[3],
                                                         cur4, csr4);

    // MEGA-GEMM: h_all = x @ [W0|W1|W2|W3|Wl_top], 128x128 tiles, CT=20
    const int RT128p8 = (((NN + 127) / 128 + 7) / 8) * 8;  // 160
    k_gemm128<<<RT128p8 * 20, 256, 0, stream>>>(x_bf, Bt_all, h_all, NH, NN, 20);

    // el/er all 4 relations
    k_el_er4<<<NN, 256, 0, stream>>>(h_all, al[0], al[1], al[2], al[3], ar[0], ar[1], ar[2], ar[3],
                                     el4, er4);

    // batched aggregate (+bias): gat4[rel] = gat_rel + bias
    dim3 gagg((NN * 64 + 255) / 256, 4);
    k_agg4<<<gagg, 256, 0, stream>>>(rp4, csr4, el4, er4, h_all, bias, gat4, alpha4);

    // serial chain: t_{i+1} = relu(t_i @ Wl_bot + xwl) + gat4[i+1]; last writes fp32 out
    const int RT64p8 = (((NN + 63) / 64 + 7) / 8) * 8;  // 320
    const int NB = RT64p8 * 4;
    // i=0: A = gat4[0] (= gat_0 + bias = t_0), write t_A (= t_1)
    k_chain<<<NB, 256, 0, stream>>>(gat4, WlTb, h_all, gat4 + (size_t)1 * NN * DD, t_A, nullptr,
                                    NN);
    // i=1: A = t_A, write t_B (= t_2)
    k_chain<<<NB, 256, 0, stream>>>(t_A, WlTb, h_all, gat4 + (size_t)2 * NN * DD, t_B, nullptr,
                                    NN);
    // i=2: A = t_B, write t_A (= t_3)
    k_chain<<<NB, 256, 0, stream>>>(t_B, WlTb, h_all, gat4 + (size_t)3 * NN * DD, t_A, nullptr,
                                    NN);
    // i=3: A = t_A, write fp32 out
    k_chain<<<NB, 256, 0, stream>>>(t_A, WlTb, h_all, nullptr, nullptr, out, NN);
}